// Round 3
// baseline (640.004 us; speedup 1.0000x reference)
//
#include <hip/hip_runtime.h>

typedef unsigned short u16;
typedef unsigned int u32;
typedef short v8s __attribute__((ext_vector_type(8)));
typedef float v4f __attribute__((ext_vector_type(4)));

__device__ __forceinline__ float b2f(u16 v) {
    return __uint_as_float(((u32)v) << 16);
}
__device__ __forceinline__ u16 f2b(float f) {
    u32 u = __float_as_uint(f);
    return (u16)((u + 0x7FFFu + ((u >> 16) & 1u)) >> 16);
}
// dual-dtype scalar read of logical element i
__device__ __forceinline__ float ldin(const void* p, size_t i, int isf32) {
    return isf32 ? ((const float*)p)[i] : b2f(((const u16*)p)[i]);
}

// ---------------- dtype detect: bf16 vs f32 reinterpretation ----------------
__global__ void detect_k(const void* x, int* flag) {
    __shared__ int cnt;
    if (threadIdx.x == 0) cnt = 0;
    __syncthreads();
    const u16* p = (const u16*)x;
    int bad = 0;
    for (int i = threadIdx.x; i < 4096; i += 256) {
        int e = (p[i] >> 7) & 0xFF;
        if (e != 0 && (e < 100 || e > 140)) bad++;
    }
    atomicAdd(&cnt, bad);
    __syncthreads();
    if (threadIdx.x == 0) *flag = (cnt > 256) ? 1 : 0;
}

// ---------------- convert to bf16 (grid-stride) ----------------
__global__ void cvt_k(const void* __restrict__ src, u16* __restrict__ dst, int n,
                      const int* __restrict__ flag) {
    const int isf32 = *flag;
    for (int i = blockIdx.x * 256 + threadIdx.x; i < n; i += gridDim.x * 256)
        dst[i] = isf32 ? f2b(((const float*)src)[i]) : ((const u16*)src)[i];
}

// ---------------- transpose+convert: in[R][C] -> out[C][R] bf16 ----------------
__global__ void transpose_k(const void* __restrict__ in, u16* __restrict__ out, int R, int C,
                            const int* __restrict__ flag) {
    __shared__ u16 t[32][33];
    const int isf32 = *flag;
    const int c0 = blockIdx.x * 32, r0 = blockIdx.y * 32;
    for (int i = threadIdx.y; i < 32; i += 8) {
        size_t idx = (size_t)(r0 + i) * C + c0 + threadIdx.x;
        t[i][threadIdx.x] = isf32 ? f2b(((const float*)in)[idx]) : ((const u16*)in)[idx];
    }
    __syncthreads();
    for (int i = threadIdx.y; i < 32; i += 8)
        out[(size_t)(c0 + i) * R + r0 + threadIdx.x] = t[threadIdx.x][i];
}

// ---------------- layernorm: one wave per 1024-elem row (bf16 in ws) ----------------
__global__ __launch_bounds__(256) void layernorm_k(const u16* __restrict__ x,
                                                   const u16* __restrict__ g,
                                                   const u16* __restrict__ bta,
                                                   u16* __restrict__ out) {
    const int wid = threadIdx.x >> 6, lane = threadIdx.x & 63;
    const size_t row = (size_t)blockIdx.x * 4 + wid;
    const u16* xr = x + row * 1024 + lane * 16;
    u16 v[16];
    *(uint4*)&v[0] = *(const uint4*)xr;
    *(uint4*)&v[8] = *(const uint4*)(xr + 8);
    float f[16], s = 0.f, sq = 0.f;
#pragma unroll
    for (int i = 0; i < 16; i++) { f[i] = b2f(v[i]); s += f[i]; sq += f[i] * f[i]; }
#pragma unroll
    for (int d = 1; d < 64; d <<= 1) { s += __shfl_xor(s, d, 64); sq += __shfl_xor(sq, d, 64); }
    const float mean = s * (1.f / 1024.f);
    const float var = sq * (1.f / 1024.f) - mean * mean;
    const float rstd = rsqrtf(var + 1e-5f);
    u16 gv[16], bv[16];
    *(uint4*)&gv[0] = *(const uint4*)(g + lane * 16);
    *(uint4*)&gv[8] = *(const uint4*)(g + lane * 16 + 8);
    *(uint4*)&bv[0] = *(const uint4*)(bta + lane * 16);
    *(uint4*)&bv[8] = *(const uint4*)(bta + lane * 16 + 8);
    u16 ov[16];
#pragma unroll
    for (int i = 0; i < 16; i++) ov[i] = f2b((f[i] - mean) * rstd * b2f(gv[i]) + b2f(bv[i]));
    u16* orow = out + row * 1024 + lane * 16;
    *(uint4*)orow = *(uint4*)&ov[0];
    *(uint4*)(orow + 8) = *(uint4*)&ov[8];
}

// ---------------- GEMM: C[M][N] = A[M][K] @ Bt[N][K]^T + bias (+gelu) (+res) ----------------
// outf32: nullptr -> bf16 store; else runtime flag selects f32/bf16 store.
__global__ __launch_bounds__(256) void gemm_bt_k(const u16* __restrict__ A,
                                                 const u16* __restrict__ Bt,
                                                 const u16* __restrict__ bias,
                                                 const u16* __restrict__ res,
                                                 void* __restrict__ C,
                                                 int M, int N, int K, int do_gelu,
                                                 const int* __restrict__ outf32) {
    __shared__ __align__(16) u16 As[128 * 32];
    __shared__ __align__(16) u16 Bs[128 * 32];
    const int tid = threadIdx.x;
    const int wid = tid >> 6, lane = tid & 63;
    const int lg = lane >> 4, lm = lane & 15;
    const int wr = wid >> 1, wc = wid & 1;
    const int m0 = blockIdx.y * 128, n0 = blockIdx.x * 128;

    const v4f vzero = {0.f, 0.f, 0.f, 0.f};
    v4f acc[4][4];
#pragma unroll
    for (int i = 0; i < 4; i++)
#pragma unroll
        for (int j = 0; j < 4; j++) acc[i][j] = vzero;

    const int srow = tid >> 2;           // 0..63
    const int scol = (tid & 3) * 8;      // 0,8,16,24
    const u16* Ag = A + (size_t)(m0 + srow) * K + scol;
    const u16* Bg = Bt + (size_t)(n0 + srow) * K + scol;
    // tid*8 == srow*32 + scol  -> row-major [row][32] tile layout in LDS
    for (int k0 = 0; k0 < K; k0 += 32) {
        v8s a0 = *(const v8s*)(Ag + k0);
        v8s a1 = *(const v8s*)(Ag + (size_t)64 * K + k0);
        v8s b0 = *(const v8s*)(Bg + k0);
        v8s b1 = *(const v8s*)(Bg + (size_t)64 * K + k0);
        __syncthreads();
        *(v8s*)&As[tid * 8] = a0;
        *(v8s*)&As[2048 + tid * 8] = a1;
        *(v8s*)&Bs[tid * 8] = b0;
        *(v8s*)&Bs[2048 + tid * 8] = b1;
        __syncthreads();
        v8s af[4], bf[4];
#pragma unroll
        for (int i = 0; i < 4; i++) af[i] = *(const v8s*)&As[(wr * 64 + i * 16 + lm) * 32 + lg * 8];
#pragma unroll
        for (int j = 0; j < 4; j++) bf[j] = *(const v8s*)&Bs[(wc * 64 + j * 16 + lm) * 32 + lg * 8];
#pragma unroll
        for (int i = 0; i < 4; i++)
#pragma unroll
            for (int j = 0; j < 4; j++)
                acc[i][j] = __builtin_amdgcn_mfma_f32_16x16x32_bf16(af[i], bf[j], acc[i][j], 0, 0, 0);
    }

    const int of32 = outf32 ? *outf32 : 0;
#pragma unroll
    for (int i = 0; i < 4; i++) {
#pragma unroll
        for (int r = 0; r < 4; r++) {
            const int row = m0 + wr * 64 + i * 16 + lg * 4 + r;
            const size_t rb = (size_t)row * N;
#pragma unroll
            for (int j = 0; j < 4; j++) {
                const int col = n0 + wc * 64 + j * 16 + lm;
                float v = acc[i][j][r] + b2f(bias[col]);
                if (do_gelu) v = 0.5f * v * (1.0f + erff(v * 0.70710678118f));
                if (res) v += b2f(res[rb + col]);
                if (of32) ((float*)C)[rb + col] = v;
                else ((u16*)C)[rb + col] = f2b(v);
            }
        }
    }
}

// ---------------- flash attention (causal), qkv[B*T][3072] -> out[B*T][1024] ----------------
__global__ __launch_bounds__(256) void attn_k(const u16* __restrict__ qkv, u16* __restrict__ out) {
    __shared__ __align__(16) u16 Ks[32 * 64];    // K tile [key][d]
    __shared__ __align__(16) u16 Vts[64 * 32];   // V tile transposed [d][key]
    __shared__ __align__(16) u16 Ps[4][16 * 32]; // per-wave P transpose buffer
    const int tid = threadIdx.x;
    const int wid = tid >> 6, lane = tid & 63;
    const int lg = lane >> 4, lm = lane & 15;
    const int bh = blockIdx.y, b = bh >> 4, h = bh & 15;
    const int q0 = blockIdx.x * 64;
    const int qw = q0 + wid * 16;
    const size_t tokbase = (size_t)b * 2048;
    const v4f vzero = {0.f, 0.f, 0.f, 0.f};

    v8s aq[2];
    {
        const u16* qp = qkv + (tokbase + qw + lm) * 3072 + h * 64 + lg * 8;
        aq[0] = *(const v8s*)qp;
        aq[1] = *(const v8s*)(qp + 32);
    }
    float m_run[4], l_run[4];
    v4f o[4];
#pragma unroll
    for (int r = 0; r < 4; r++) { m_run[r] = -1e30f; l_run[r] = 0.f; }
#pragma unroll
    for (int dt = 0; dt < 4; dt++) o[dt] = vzero;

    const int krow = tid >> 3, kc = (tid & 7) * 8;   // K staging coords
    const int vkey = tid & 31, vc = tid >> 5;        // V staging coords
    const int ktiles = blockIdx.x * 2 + 2;
    for (int kt = 0; kt < ktiles; ++kt) {
        const int k0 = kt * 32;
        v8s kv = *(const v8s*)(qkv + (tokbase + k0 + krow) * 3072 + 1024 + h * 64 + kc);
        v8s vv = *(const v8s*)(qkv + (tokbase + k0 + vkey) * 3072 + 2048 + h * 64 + vc * 8);
        __syncthreads();
        *(v8s*)&Ks[tid * 8] = kv;   // tid*8 == krow*64 + kc
        {
            u16 tmp[8];
            *(v8s*)tmp = vv;
#pragma unroll
            for (int i = 0; i < 8; i++) Vts[(vc * 8 + i) * 32 + vkey] = tmp[i];
        }
        __syncthreads();
        if (k0 <= qw + 15) {
            v4f s0 = vzero, s1 = vzero;
#pragma unroll
            for (int kk = 0; kk < 2; kk++) {
                v8s b0 = *(const v8s*)&Ks[lm * 64 + kk * 32 + lg * 8];
                v8s b1 = *(const v8s*)&Ks[(16 + lm) * 64 + kk * 32 + lg * 8];
                s0 = __builtin_amdgcn_mfma_f32_16x16x32_bf16(aq[kk], b0, s0, 0, 0, 0);
                s1 = __builtin_amdgcn_mfma_f32_16x16x32_bf16(aq[kk], b1, s1, 0, 0, 0);
            }
#pragma unroll
            for (int r = 0; r < 4; r++) {
                const int qrow = qw + lg * 4 + r;
                float v0 = s0[r] * 0.125f;
                if (k0 + lm > qrow) v0 = -1e30f;
                float v1 = s1[r] * 0.125f;
                if (k0 + 16 + lm > qrow) v1 = -1e30f;
                float mt = fmaxf(v0, v1);
#pragma unroll
                for (int d = 1; d < 16; d <<= 1) mt = fmaxf(mt, __shfl_xor(mt, d, 64));
                const float mn = fmaxf(m_run[r], mt);
                const float al = expf(m_run[r] - mn);
                m_run[r] = mn;
                const float p0 = expf(v0 - mn), p1 = expf(v1 - mn);
                float rs = p0 + p1;
#pragma unroll
                for (int d = 1; d < 16; d <<= 1) rs += __shfl_xor(rs, d, 64);
                l_run[r] = l_run[r] * al + rs;
#pragma unroll
                for (int dt = 0; dt < 4; dt++) o[dt][r] *= al;
                Ps[wid][(lg * 4 + r) * 32 + lm] = f2b(p0);
                Ps[wid][(lg * 4 + r) * 32 + 16 + lm] = f2b(p1);
            }
            asm volatile("s_waitcnt lgkmcnt(0)" ::: "memory"); // wave-local P round-trip
            v8s ap = *(const v8s*)&Ps[wid][lm * 32 + lg * 8];
#pragma unroll
            for (int dt = 0; dt < 4; dt++) {
                v8s bv = *(const v8s*)&Vts[(dt * 16 + lm) * 32 + lg * 8];
                o[dt] = __builtin_amdgcn_mfma_f32_16x16x32_bf16(ap, bv, o[dt], 0, 0, 0);
            }
        }
    }
#pragma unroll
    for (int r = 0; r < 4; r++) {
        const float inv = 1.0f / l_run[r];
        const size_t rowb = (tokbase + qw + lg * 4 + r) * 1024 + h * 64;
#pragma unroll
        for (int dt = 0; dt < 4; dt++) out[rowb + dt * 16 + lm] = f2b(o[dt][r] * inv);
    }
}

extern "C" void kernel_launch(void* const* d_in, const int* in_sizes, int n_in,
                              void* d_out, int out_size, void* d_ws, size_t ws_size,
                              hipStream_t stream) {
    const void* x      = d_in[0];
    const void* ln1_g  = d_in[1];
    const void* ln1_b  = d_in[2];
    const void* w_attn = d_in[3];
    const void* b_attn = d_in[4];
    const void* w_proj = d_in[5];
    const void* b_proj = d_in[6];
    const void* ln2_g  = d_in[7];
    const void* ln2_b  = d_in[8];
    const void* w_fc   = d_in[9];
    const void* b_fc   = d_in[10];
    const void* w_fc2  = d_in[11];
    const void* b_fc2  = d_in[12];

    u16* ws = (u16*)d_ws;
    const size_t Mi = 1u << 20;
    u16* xb       = ws;                 // [0,4Mi)
    u16* ln_buf   = ws + 4 * Mi;        // [4,8)
    u16* h_buf    = ws + 8 * Mi;        // [8,12)
    u16* wT_attn  = ws + 12 * Mi;       // [12,15)
    u16* wT_proj  = ws + 15 * Mi;       // [15,16)
    u16* wT_fc    = ws + 16 * Mi;       // [16,20)
    u16* wT_fc2   = ws + 20 * Mi;       // [20,24)
    u16* bb       = ws + 24 * Mi;       // 4 bias slots of 4096
    u16* bb_attn = bb, *bb_proj = bb + 4096, *bb_fc = bb + 8192, *bb_fc2 = bb + 12288;
    u16* gsmall   = bb + 16384;         // ln1_g, ln1_b, ln2_g, ln2_b: 4 x 1024
    u16* g_ln1g = gsmall, *g_ln1b = gsmall + 1024, *g_ln2g = gsmall + 2048, *g_ln2b = gsmall + 3072;
    int* flag     = (int*)(bb + 24576);
    u16* qkv      = ws + 25 * Mi;       // [25,37) dead after attn
    u16* attn_buf = ws + 37 * Mi;       // [37,41) dead after proj
    u16* fc_buf   = ws + 25 * Mi;       // [25,41) overlays dead qkv+attn_buf
    // total: 41 Mi u16 = 82 MiB

    detect_k<<<1, 256, 0, stream>>>(x, flag);

    cvt_k<<<4096, 256, 0, stream>>>(x, xb, 4 * Mi, flag);
    cvt_k<<<12, 256, 0, stream>>>(b_attn, bb_attn, 3072, flag);
    cvt_k<<<4, 256, 0, stream>>>(b_proj, bb_proj, 1024, flag);
    cvt_k<<<16, 256, 0, stream>>>(b_fc, bb_fc, 4096, flag);
    cvt_k<<<4, 256, 0, stream>>>(b_fc2, bb_fc2, 1024, flag);
    cvt_k<<<4, 256, 0, stream>>>(ln1_g, g_ln1g, 1024, flag);
    cvt_k<<<4, 256, 0, stream>>>(ln1_b, g_ln1b, 1024, flag);
    cvt_k<<<4, 256, 0, stream>>>(ln2_g, g_ln2g, 1024, flag);
    cvt_k<<<4, 256, 0, stream>>>(ln2_b, g_ln2b, 1024, flag);

    dim3 tb(32, 8);
    transpose_k<<<dim3(96, 32), tb, 0, stream>>>(w_attn, wT_attn, 1024, 3072, flag);
    transpose_k<<<dim3(32, 32), tb, 0, stream>>>(w_proj, wT_proj, 1024, 1024, flag);
    transpose_k<<<dim3(128, 32), tb, 0, stream>>>(w_fc, wT_fc, 1024, 4096, flag);
    transpose_k<<<dim3(32, 128), tb, 0, stream>>>(w_fc2, wT_fc2, 4096, 1024, flag);

    layernorm_k<<<1024, 256, 0, stream>>>(xb, g_ln1g, g_ln1b, ln_buf);
    gemm_bt_k<<<dim3(24, 32), 256, 0, stream>>>(ln_buf, wT_attn, bb_attn, nullptr, qkv,
                                                4096, 3072, 1024, 0, nullptr);
    attn_k<<<dim3(32, 32), 256, 0, stream>>>(qkv, attn_buf);
    gemm_bt_k<<<dim3(8, 32), 256, 0, stream>>>(attn_buf, wT_proj, bb_proj, xb, h_buf,
                                               4096, 1024, 1024, 0, nullptr);
    layernorm_k<<<1024, 256, 0, stream>>>(h_buf, g_ln2g, g_ln2b, ln_buf);
    gemm_bt_k<<<dim3(32, 32), 256, 0, stream>>>(ln_buf, wT_fc, bb_fc, nullptr, fc_buf,
                                                4096, 4096, 1024, 1, nullptr);
    gemm_bt_k<<<dim3(8, 32), 256, 0, stream>>>(fc_buf, wT_fc2, bb_fc2, h_buf, d_out,
                                               4096, 1024, 4096, 0, flag);
}

// Round 4
// 598.003 us; speedup vs baseline: 1.0702x; 1.0702x over previous
//
#include <hip/hip_runtime.h>

typedef unsigned short u16;
typedef unsigned int u32;
typedef short v8s __attribute__((ext_vector_type(8)));
typedef short v4s __attribute__((ext_vector_type(4)));
typedef float v4f __attribute__((ext_vector_type(4)));

__device__ __forceinline__ float b2f(u16 v) {
    return __uint_as_float(((u32)v) << 16);
}
__device__ __forceinline__ u16 f2b(float f) {
    u32 u = __float_as_uint(f);
    return (u16)((u + 0x7FFFu + ((u >> 16) & 1u)) >> 16);
}

// ---------------- dtype detect: bf16 vs f32 reinterpretation ----------------
__global__ void detect_k(const void* x, int* flag) {
    __shared__ int cnt;
    if (threadIdx.x == 0) cnt = 0;
    __syncthreads();
    const u16* p = (const u16*)x;
    int bad = 0;
    for (int i = threadIdx.x; i < 4096; i += 256) {
        int e = (p[i] >> 7) & 0xFF;
        if (e != 0 && (e < 100 || e > 140)) bad++;
    }
    atomicAdd(&cnt, bad);
    __syncthreads();
    if (threadIdx.x == 0) *flag = (cnt > 256) ? 1 : 0;
}

// ---------------- convert to bf16 (grid-stride) ----------------
__global__ void cvt_k(const void* __restrict__ src, u16* __restrict__ dst, int n,
                      const int* __restrict__ flag) {
    const int isf32 = *flag;
    for (int i = blockIdx.x * 256 + threadIdx.x; i < n; i += gridDim.x * 256)
        dst[i] = isf32 ? f2b(((const float*)src)[i]) : ((const u16*)src)[i];
}

// ---------------- transpose+convert: in[R][C] -> out[C][R] bf16 ----------------
__global__ void transpose_k(const void* __restrict__ in, u16* __restrict__ out, int R, int C,
                            const int* __restrict__ flag) {
    __shared__ u16 t[32][33];
    const int isf32 = *flag;
    const int c0 = blockIdx.x * 32, r0 = blockIdx.y * 32;
    for (int i = threadIdx.y; i < 32; i += 8) {
        size_t idx = (size_t)(r0 + i) * C + c0 + threadIdx.x;
        t[i][threadIdx.x] = isf32 ? f2b(((const float*)in)[idx]) : ((const u16*)in)[idx];
    }
    __syncthreads();
    for (int i = threadIdx.y; i < 32; i += 8)
        out[(size_t)(c0 + i) * R + r0 + threadIdx.x] = t[threadIdx.x][i];
}

// ---------------- layernorm: one wave per 1024-elem row (bf16 in ws) ----------------
__global__ __launch_bounds__(256) void layernorm_k(const u16* __restrict__ x,
                                                   const u16* __restrict__ g,
                                                   const u16* __restrict__ bta,
                                                   u16* __restrict__ out) {
    const int wid = threadIdx.x >> 6, lane = threadIdx.x & 63;
    const size_t row = (size_t)blockIdx.x * 4 + wid;
    const u16* xr = x + row * 1024 + lane * 16;
    u16 v[16];
    *(uint4*)&v[0] = *(const uint4*)xr;
    *(uint4*)&v[8] = *(const uint4*)(xr + 8);
    float f[16], s = 0.f, sq = 0.f;
#pragma unroll
    for (int i = 0; i < 16; i++) { f[i] = b2f(v[i]); s += f[i]; sq += f[i] * f[i]; }
#pragma unroll
    for (int d = 1; d < 64; d <<= 1) { s += __shfl_xor(s, d, 64); sq += __shfl_xor(sq, d, 64); }
    const float mean = s * (1.f / 1024.f);
    const float var = sq * (1.f / 1024.f) - mean * mean;
    const float rstd = rsqrtf(var + 1e-5f);
    u16 gv[16], bv[16];
    *(uint4*)&gv[0] = *(const uint4*)(g + lane * 16);
    *(uint4*)&gv[8] = *(const uint4*)(g + lane * 16 + 8);
    *(uint4*)&bv[0] = *(const uint4*)(bta + lane * 16);
    *(uint4*)&bv[8] = *(const uint4*)(bta + lane * 16 + 8);
    u16 ov[16];
#pragma unroll
    for (int i = 0; i < 16; i++) ov[i] = f2b((f[i] - mean) * rstd * b2f(gv[i]) + b2f(bv[i]));
    u16* orow = out + row * 1024 + lane * 16;
    *(uint4*)orow = *(uint4*)&ov[0];
    *(uint4*)(orow + 8) = *(uint4*)&ov[8];
}

// ---------------- generic GEMM: C[M][N] = A @ Bt^T + bias (+gelu) (+res) ----------------
__global__ __launch_bounds__(256) void gemm_bt_k(const u16* __restrict__ A,
                                                 const u16* __restrict__ Bt,
                                                 const u16* __restrict__ bias,
                                                 const u16* __restrict__ res,
                                                 void* __restrict__ C,
                                                 int M, int N, int K, int do_gelu,
                                                 const int* __restrict__ outf32) {
    __shared__ __align__(16) u16 As[128 * 32];
    __shared__ __align__(16) u16 Bs[128 * 32];
    const int tid = threadIdx.x;
    const int wid = tid >> 6, lane = tid & 63;
    const int lg = lane >> 4, lm = lane & 15;
    const int wr = wid >> 1, wc = wid & 1;
    const int m0 = blockIdx.y * 128, n0 = blockIdx.x * 128;

    const v4f vzero = {0.f, 0.f, 0.f, 0.f};
    v4f acc[4][4];
#pragma unroll
    for (int i = 0; i < 4; i++)
#pragma unroll
        for (int j = 0; j < 4; j++) acc[i][j] = vzero;

    const int srow = tid >> 2;
    const int scol = (tid & 3) * 8;
    const u16* Ag = A + (size_t)(m0 + srow) * K + scol;
    const u16* Bg = Bt + (size_t)(n0 + srow) * K + scol;
    for (int k0 = 0; k0 < K; k0 += 32) {
        v8s a0 = *(const v8s*)(Ag + k0);
        v8s a1 = *(const v8s*)(Ag + (size_t)64 * K + k0);
        v8s b0 = *(const v8s*)(Bg + k0);
        v8s b1 = *(const v8s*)(Bg + (size_t)64 * K + k0);
        __syncthreads();
        *(v8s*)&As[tid * 8] = a0;
        *(v8s*)&As[2048 + tid * 8] = a1;
        *(v8s*)&Bs[tid * 8] = b0;
        *(v8s*)&Bs[2048 + tid * 8] = b1;
        __syncthreads();
        v8s af[4], bf[4];
#pragma unroll
        for (int i = 0; i < 4; i++) af[i] = *(const v8s*)&As[(wr * 64 + i * 16 + lm) * 32 + lg * 8];
#pragma unroll
        for (int j = 0; j < 4; j++) bf[j] = *(const v8s*)&Bs[(wc * 64 + j * 16 + lm) * 32 + lg * 8];
#pragma unroll
        for (int i = 0; i < 4; i++)
#pragma unroll
            for (int j = 0; j < 4; j++)
                acc[i][j] = __builtin_amdgcn_mfma_f32_16x16x32_bf16(af[i], bf[j], acc[i][j], 0, 0, 0);
    }

    const int of32 = outf32 ? *outf32 : 0;
#pragma unroll
    for (int i = 0; i < 4; i++) {
#pragma unroll
        for (int r = 0; r < 4; r++) {
            const int row = m0 + wr * 64 + i * 16 + lg * 4 + r;
            const size_t rb = (size_t)row * N;
#pragma unroll
            for (int j = 0; j < 4; j++) {
                const int col = n0 + wc * 64 + j * 16 + lm;
                float v = acc[i][j][r] + b2f(bias[col]);
                if (do_gelu) v = 0.5f * v * (1.0f + erff(v * 0.70710678118f));
                if (res) v += b2f(res[rb + col]);
                if (of32) ((float*)C)[rb + col] = v;
                else ((u16*)C)[rb + col] = f2b(v);
            }
        }
    }
}

// ---------------- QKV GEMM: same core, epilogue scatters head-major Q/K + transposed V ----------------
__global__ __launch_bounds__(256) void gemm_qkv_k(const u16* __restrict__ A,
                                                  const u16* __restrict__ Bt,
                                                  const u16* __restrict__ bias,
                                                  u16* __restrict__ Qh,
                                                  u16* __restrict__ Kh,
                                                  u16* __restrict__ Vth) {
    __shared__ __align__(16) u16 As[128 * 32];
    __shared__ __align__(16) u16 Bs[128 * 32];
    const int tid = threadIdx.x;
    const int wid = tid >> 6, lane = tid & 63;
    const int lg = lane >> 4, lm = lane & 15;
    const int wr = wid >> 1, wc = wid & 1;
    const int m0 = blockIdx.y * 128, n0 = blockIdx.x * 128;
    const int K = 1024;

    const v4f vzero = {0.f, 0.f, 0.f, 0.f};
    v4f acc[4][4];
#pragma unroll
    for (int i = 0; i < 4; i++)
#pragma unroll
        for (int j = 0; j < 4; j++) acc[i][j] = vzero;

    const int srow = tid >> 2;
    const int scol = (tid & 3) * 8;
    const u16* Ag = A + (size_t)(m0 + srow) * K + scol;
    const u16* Bg = Bt + (size_t)(n0 + srow) * K + scol;
    for (int k0 = 0; k0 < K; k0 += 32) {
        v8s a0 = *(const v8s*)(Ag + k0);
        v8s a1 = *(const v8s*)(Ag + (size_t)64 * K + k0);
        v8s b0 = *(const v8s*)(Bg + k0);
        v8s b1 = *(const v8s*)(Bg + (size_t)64 * K + k0);
        __syncthreads();
        *(v8s*)&As[tid * 8] = a0;
        *(v8s*)&As[2048 + tid * 8] = a1;
        *(v8s*)&Bs[tid * 8] = b0;
        *(v8s*)&Bs[2048 + tid * 8] = b1;
        __syncthreads();
        v8s af[4], bf[4];
#pragma unroll
        for (int i = 0; i < 4; i++) af[i] = *(const v8s*)&As[(wr * 64 + i * 16 + lm) * 32 + lg * 8];
#pragma unroll
        for (int j = 0; j < 4; j++) bf[j] = *(const v8s*)&Bs[(wc * 64 + j * 16 + lm) * 32 + lg * 8];
#pragma unroll
        for (int i = 0; i < 4; i++)
#pragma unroll
            for (int j = 0; j < 4; j++)
                acc[i][j] = __builtin_amdgcn_mfma_f32_16x16x32_bf16(af[i], bf[j], acc[i][j], 0, 0, 0);
    }

    // epilogue: which tensor is wave-uniform (block spans 128 cols inside one 1024-col tensor)
    const int which = n0 >> 10;                 // 0=q 1=k 2=v
    const int h = ((n0 & 1023) >> 6) + wc;      // head
    if (which < 2) {
        u16* dst = which ? Kh : Qh;
#pragma unroll
        for (int i = 0; i < 4; i++) {
#pragma unroll
            for (int r = 0; r < 4; r++) {
                const int row = m0 + wr * 64 + i * 16 + lg * 4 + r;
                const int b = row >> 11, t = row & 2047;
                const size_t rb = ((size_t)(b * 16 + h) * 2048 + t) * 64;
#pragma unroll
                for (int j = 0; j < 4; j++) {
                    float v = acc[i][j][r] + b2f(bias[n0 + wc * 64 + j * 16 + lm]);
                    dst[rb + j * 16 + lm] = f2b(v);
                }
            }
        }
    } else {
#pragma unroll
        for (int i = 0; i < 4; i++) {
            const int t0 = m0 + wr * 64 + i * 16 + lg * 4;
            const int b = t0 >> 11, tt = t0 & 2047;
#pragma unroll
            for (int j = 0; j < 4; j++) {
                const int d = j * 16 + lm;
                const float bv_ = b2f(bias[n0 + wc * 64 + j * 16 + lm]);
                u16 pk[4];
#pragma unroll
                for (int r = 0; r < 4; r++) pk[r] = f2b(acc[i][j][r] + bv_);
                *(v4s*)&Vth[((size_t)(b * 16 + h) * 64 + d) * 2048 + tt] = *(const v4s*)pk;
            }
        }
    }
}

// ---------------- flash attention v2: head-major inputs, 128 q-rows/block, 64-key tiles ----------------
__global__ __launch_bounds__(256) void attn2_k(const u16* __restrict__ Qh,
                                               const u16* __restrict__ Kh,
                                               const u16* __restrict__ Vth,
                                               u16* __restrict__ out) {
    __shared__ __align__(16) u16 Ks[64 * 64];   // [key][d], chunk-swizzled
    __shared__ __align__(16) u16 Vts[64 * 64];  // [d][key], chunk-swizzled
    __shared__ __align__(16) u16 Ps[4][16 * 64];// per-wave P, chunk-swizzled
    const int tid = threadIdx.x;
    const int wid = tid >> 6, lane = tid & 63;
    const int lg = lane >> 4, lm = lane & 15;
    // pair-balanced mapping: slot s handles (qt, 15-qt) halves -> uniform work
    const int id = blockIdx.x;
    const int s = id & 255, hh = id >> 8;
    const int bh = s >> 3, ps = s & 7;
    const int qt = hh ? (15 - ps) : ps;
    const int q0 = qt * 128;
    const size_t qkb = (size_t)bh * 2048;
    const v4f vzero = {0.f, 0.f, 0.f, 0.f};
    const float sc = 0.18033688011f; // log2(e)/8

    int rbase[2];
    rbase[0] = q0 + wid * 16;
    rbase[1] = q0 + 64 + wid * 16;

    v8s aq[2][2];
#pragma unroll
    for (int i = 0; i < 2; i++) {
        const u16* qp = Qh + (qkb + rbase[i] + lm) * 64 + lg * 8;
        aq[i][0] = *(const v8s*)qp;
        aq[i][1] = *(const v8s*)(qp + 32);
    }
    float m_run[2][4], l_run[2][4];
    v4f o[2][4];
#pragma unroll
    for (int i = 0; i < 2; i++)
#pragma unroll
        for (int r = 0; r < 4; r++) { m_run[i][r] = -1e30f; l_run[i][r] = 0.f; }
#pragma unroll
    for (int i = 0; i < 2; i++)
#pragma unroll
        for (int dt = 0; dt < 4; dt++) o[i][dt] = vzero;

    const int kmax = q0 + 128;
    for (int k0 = 0; k0 < kmax; k0 += 64) {
        __syncthreads();
#pragma unroll
        for (int si = 0; si < 2; si++) {
            const int idx = si * 256 + tid;
            const int row = idx >> 3, c = idx & 7;
            *(v8s*)&Ks[(row << 6) + (((c ^ (row & 7)) << 3))] =
                *(const v8s*)(Kh + (qkb + k0 + row) * 64 + c * 8);
            *(v8s*)&Vts[(row << 6) + (((c ^ (row & 7)) << 3))] =
                *(const v8s*)(Vth + ((size_t)bh * 64 + row) * 2048 + k0 + c * 8);
        }
        __syncthreads();
#pragma unroll
        for (int i = 0; i < 2; i++) {
            if (k0 > rbase[i] + 15) continue;  // rowtile fully masked (wave-uniform)
            v4f sacc[4];
#pragma unroll
            for (int kt = 0; kt < 4; kt++) sacc[kt] = vzero;
#pragma unroll
            for (int kt = 0; kt < 4; kt++)
#pragma unroll
                for (int kk = 0; kk < 2; kk++) {
                    v8s bfr = *(const v8s*)&Ks[((kt * 16 + lm) << 6) + (((kk * 4 + lg) ^ (lm & 7)) << 3)];
                    sacc[kt] = __builtin_amdgcn_mfma_f32_16x16x32_bf16(aq[i][kk], bfr, sacc[kt], 0, 0, 0);
                }
            const bool needmask = (k0 + 63 > rbase[i]);
            const int prow = lg * 4;
#pragma unroll
            for (int r = 0; r < 4; r++) {
                float v[4];
#pragma unroll
                for (int kt = 0; kt < 4; kt++) v[kt] = sacc[kt][r] * sc;
                if (needmask) {
                    const int qrow = rbase[i] + lg * 4 + r;
#pragma unroll
                    for (int kt = 0; kt < 4; kt++)
                        if (k0 + kt * 16 + lm > qrow) v[kt] = -1e30f;
                }
                float mt = fmaxf(fmaxf(v[0], v[1]), fmaxf(v[2], v[3]));
#pragma unroll
                for (int d = 1; d < 16; d <<= 1) mt = fmaxf(mt, __shfl_xor(mt, d, 64));
                const float mn = fmaxf(m_run[i][r], mt);
                const float al = exp2f(m_run[i][r] - mn);
                m_run[i][r] = mn;
                float p[4], rs = 0.f;
#pragma unroll
                for (int kt = 0; kt < 4; kt++) { p[kt] = exp2f(v[kt] - mn); rs += p[kt]; }
#pragma unroll
                for (int d = 1; d < 16; d <<= 1) rs += __shfl_xor(rs, d, 64);
                l_run[i][r] = l_run[i][r] * al + rs;
#pragma unroll
                for (int dt = 0; dt < 4; dt++) o[i][dt][r] *= al;
                const int pr = prow + r, rx = pr & 7;
#pragma unroll
                for (int kt = 0; kt < 4; kt++) {
                    const int chunk = (kt << 1) | (lm >> 3);
                    Ps[wid][(pr << 6) + (((chunk ^ rx) << 3) | (lm & 7))] = f2b(p[kt]);
                }
            }
            asm volatile("s_waitcnt lgkmcnt(0)" ::: "memory");
            v8s ap[2];
#pragma unroll
            for (int kk = 0; kk < 2; kk++)
                ap[kk] = *(const v8s*)&Ps[wid][(lm << 6) + (((kk * 4 + lg) ^ (lm & 7)) << 3)];
#pragma unroll
            for (int dt = 0; dt < 4; dt++)
#pragma unroll
                for (int kk = 0; kk < 2; kk++) {
                    v8s bvf = *(const v8s*)&Vts[((dt * 16 + lm) << 6) + (((kk * 4 + lg) ^ (lm & 7)) << 3)];
                    o[i][dt] = __builtin_amdgcn_mfma_f32_16x16x32_bf16(ap[kk], bvf, o[i][dt], 0, 0, 0);
                }
        }
    }
    const int b = bh >> 4, h = bh & 15;
#pragma unroll
    for (int i = 0; i < 2; i++) {
#pragma unroll
        for (int r = 0; r < 4; r++) {
            const float inv = 1.0f / l_run[i][r];
            const int qrow = rbase[i] + lg * 4 + r;
            const size_t rowb = ((size_t)b * 2048 + qrow) * 1024 + h * 64;
#pragma unroll
            for (int dt = 0; dt < 4; dt++) out[rowb + dt * 16 + lm] = f2b(o[i][dt][r] * inv);
        }
    }
}

extern "C" void kernel_launch(void* const* d_in, const int* in_sizes, int n_in,
                              void* d_out, int out_size, void* d_ws, size_t ws_size,
                              hipStream_t stream) {
    const void* x      = d_in[0];
    const void* ln1_g  = d_in[1];
    const void* ln1_b  = d_in[2];
    const void* w_attn = d_in[3];
    const void* b_attn = d_in[4];
    const void* w_proj = d_in[5];
    const void* b_proj = d_in[6];
    const void* ln2_g  = d_in[7];
    const void* ln2_b  = d_in[8];
    const void* w_fc   = d_in[9];
    const void* b_fc   = d_in[10];
    const void* w_fc2  = d_in[11];
    const void* b_fc2  = d_in[12];

    u16* ws = (u16*)d_ws;
    const size_t Mi = 1u << 20;
    u16* xb       = ws;                 // [0,4Mi)
    u16* ln_buf   = ws + 4 * Mi;        // [4,8)
    u16* h_buf    = ws + 8 * Mi;        // [8,12)
    u16* wT_attn  = ws + 12 * Mi;       // [12,15)
    u16* wT_proj  = ws + 15 * Mi;       // [15,16)
    u16* wT_fc    = ws + 16 * Mi;       // [16,20)
    u16* wT_fc2   = ws + 20 * Mi;       // [20,24)
    u16* bb       = ws + 24 * Mi;
    u16* bb_attn = bb, *bb_proj = bb + 4096, *bb_fc = bb + 8192, *bb_fc2 = bb + 12288;
    u16* gsmall   = bb + 16384;
    u16* g_ln1g = gsmall, *g_ln1b = gsmall + 1024, *g_ln2g = gsmall + 2048, *g_ln2b = gsmall + 3072;
    int* flag     = (int*)(bb + 24576);
    u16* Qh       = ws + 25 * Mi;       // [25,29) head-major Q
    u16* Kh       = ws + 29 * Mi;       // [29,33)
    u16* Vth      = ws + 33 * Mi;       // [33,37) V transposed [bh][d][t]
    u16* attn_buf = ws + 37 * Mi;       // [37,41)
    u16* fc_buf   = ws + 25 * Mi;       // [25,41) overlays dead Qh/Kh/Vth/attn_buf
    // total 41 Mi u16 = 82 MiB (same footprint as round 3)

    detect_k<<<1, 256, 0, stream>>>(x, flag);

    cvt_k<<<4096, 256, 0, stream>>>(x, xb, 4 * Mi, flag);
    cvt_k<<<12, 256, 0, stream>>>(b_attn, bb_attn, 3072, flag);
    cvt_k<<<4, 256, 0, stream>>>(b_proj, bb_proj, 1024, flag);
    cvt_k<<<16, 256, 0, stream>>>(b_fc, bb_fc, 4096, flag);
    cvt_k<<<4, 256, 0, stream>>>(b_fc2, bb_fc2, 1024, flag);
    cvt_k<<<4, 256, 0, stream>>>(ln1_g, g_ln1g, 1024, flag);
    cvt_k<<<4, 256, 0, stream>>>(ln1_b, g_ln1b, 1024, flag);
    cvt_k<<<4, 256, 0, stream>>>(ln2_g, g_ln2g, 1024, flag);
    cvt_k<<<4, 256, 0, stream>>>(ln2_b, g_ln2b, 1024, flag);

    dim3 tb(32, 8);
    transpose_k<<<dim3(96, 32), tb, 0, stream>>>(w_attn, wT_attn, 1024, 3072, flag);
    transpose_k<<<dim3(32, 32), tb, 0, stream>>>(w_proj, wT_proj, 1024, 1024, flag);
    transpose_k<<<dim3(128, 32), tb, 0, stream>>>(w_fc, wT_fc, 1024, 4096, flag);
    transpose_k<<<dim3(32, 128), tb, 0, stream>>>(w_fc2, wT_fc2, 4096, 1024, flag);

    layernorm_k<<<1024, 256, 0, stream>>>(xb, g_ln1g, g_ln1b, ln_buf);
    gemm_qkv_k<<<dim3(24, 32), 256, 0, stream>>>(ln_buf, wT_attn, bb_attn, Qh, Kh, Vth);
    attn2_k<<<512, 256, 0, stream>>>(Qh, Kh, Vth, attn_buf);
    gemm_bt_k<<<dim3(8, 32), 256, 0, stream>>>(attn_buf, wT_proj, bb_proj, xb, h_buf,
                                               4096, 1024, 1024, 0, nullptr);
    layernorm_k<<<1024, 256, 0, stream>>>(h_buf, g_ln2g, g_ln2b, ln_buf);
    gemm_bt_k<<<dim3(32, 32), 256, 0, stream>>>(ln_buf, wT_fc, bb_fc, nullptr, fc_buf,
                                                4096, 4096, 1024, 1, nullptr);
    gemm_bt_k<<<dim3(8, 32), 256, 0, stream>>>(fc_buf, wT_fc2, bb_fc2, h_buf, d_out,
                                               4096, 1024, 4096, 0, flag);
}

// Round 5
// 589.927 us; speedup vs baseline: 1.0849x; 1.0137x over previous
//
#include <hip/hip_runtime.h>

typedef unsigned short u16;
typedef unsigned int u32;
typedef short v8s __attribute__((ext_vector_type(8)));
typedef short v4s __attribute__((ext_vector_type(4)));
typedef float v4f __attribute__((ext_vector_type(4)));

__device__ __forceinline__ float b2f(u16 v) {
    return __uint_as_float(((u32)v) << 16);
}
__device__ __forceinline__ u16 f2b(float f) {
    u32 u = __float_as_uint(f);
    return (u16)((u + 0x7FFFu + ((u >> 16) & 1u)) >> 16);
}

// ---------------- dtype detect: bf16 vs f32 reinterpretation ----------------
__global__ void detect_k(const void* x, int* flag) {
    __shared__ int cnt;
    if (threadIdx.x == 0) cnt = 0;
    __syncthreads();
    const u16* p = (const u16*)x;
    int bad = 0;
    for (int i = threadIdx.x; i < 4096; i += 256) {
        int e = (p[i] >> 7) & 0xFF;
        if (e != 0 && (e < 100 || e > 140)) bad++;
    }
    atomicAdd(&cnt, bad);
    __syncthreads();
    if (threadIdx.x == 0) *flag = (cnt > 256) ? 1 : 0;
}

// ---------------- convert to bf16 (grid-stride) ----------------
__global__ void cvt_k(const void* __restrict__ src, u16* __restrict__ dst, int n,
                      const int* __restrict__ flag) {
    const int isf32 = *flag;
    for (int i = blockIdx.x * 256 + threadIdx.x; i < n; i += gridDim.x * 256)
        dst[i] = isf32 ? f2b(((const float*)src)[i]) : ((const u16*)src)[i];
}

// ---------------- transpose+convert: in[R][C] -> out[C][R] bf16 ----------------
__global__ void transpose_k(const void* __restrict__ in, u16* __restrict__ out, int R, int C,
                            const int* __restrict__ flag) {
    __shared__ u16 t[32][33];
    const int isf32 = *flag;
    const int c0 = blockIdx.x * 32, r0 = blockIdx.y * 32;
    for (int i = threadIdx.y; i < 32; i += 8) {
        size_t idx = (size_t)(r0 + i) * C + c0 + threadIdx.x;
        t[i][threadIdx.x] = isf32 ? f2b(((const float*)in)[idx]) : ((const u16*)in)[idx];
    }
    __syncthreads();
    for (int i = threadIdx.y; i < 32; i += 8)
        out[(size_t)(c0 + i) * R + r0 + threadIdx.x] = t[threadIdx.x][i];
}

// ---------------- layernorm: one wave per 1024-elem row (bf16 in ws) ----------------
__global__ __launch_bounds__(256) void layernorm_k(const u16* __restrict__ x,
                                                   const u16* __restrict__ g,
                                                   const u16* __restrict__ bta,
                                                   u16* __restrict__ out) {
    const int wid = threadIdx.x >> 6, lane = threadIdx.x & 63;
    const size_t row = (size_t)blockIdx.x * 4 + wid;
    const u16* xr = x + row * 1024 + lane * 16;
    u16 v[16];
    *(uint4*)&v[0] = *(const uint4*)xr;
    *(uint4*)&v[8] = *(const uint4*)(xr + 8);
    float f[16], s = 0.f, sq = 0.f;
#pragma unroll
    for (int i = 0; i < 16; i++) { f[i] = b2f(v[i]); s += f[i]; sq += f[i] * f[i]; }
#pragma unroll
    for (int d = 1; d < 64; d <<= 1) { s += __shfl_xor(s, d, 64); sq += __shfl_xor(sq, d, 64); }
    const float mean = s * (1.f / 1024.f);
    const float var = sq * (1.f / 1024.f) - mean * mean;
    const float rstd = rsqrtf(var + 1e-5f);
    u16 gv[16], bv[16];
    *(uint4*)&gv[0] = *(const uint4*)(g + lane * 16);
    *(uint4*)&gv[8] = *(const uint4*)(g + lane * 16 + 8);
    *(uint4*)&bv[0] = *(const uint4*)(bta + lane * 16);
    *(uint4*)&bv[8] = *(const uint4*)(bta + lane * 16 + 8);
    u16 ov[16];
#pragma unroll
    for (int i = 0; i < 16; i++) ov[i] = f2b((f[i] - mean) * rstd * b2f(gv[i]) + b2f(bv[i]));
    u16* orow = out + row * 1024 + lane * 16;
    *(uint4*)orow = *(uint4*)&ov[0];
    *(uint4*)(orow + 8) = *(uint4*)&ov[8];
}

// ---------------- generic GEMM: C[M][N] = A @ Bt^T + bias (+gelu) (+res) ----------------
__global__ __launch_bounds__(256) void gemm_bt_k(const u16* __restrict__ A,
                                                 const u16* __restrict__ Bt,
                                                 const u16* __restrict__ bias,
                                                 const u16* __restrict__ res,
                                                 void* __restrict__ C,
                                                 int M, int N, int K, int do_gelu,
                                                 const int* __restrict__ outf32) {
    __shared__ __align__(16) u16 As[128 * 32];
    __shared__ __align__(16) u16 Bs[128 * 32];
    const int tid = threadIdx.x;
    const int wid = tid >> 6, lane = tid & 63;
    const int lg = lane >> 4, lm = lane & 15;
    const int wr = wid >> 1, wc = wid & 1;
    const int m0 = blockIdx.y * 128, n0 = blockIdx.x * 128;

    const v4f vzero = {0.f, 0.f, 0.f, 0.f};
    v4f acc[4][4];
#pragma unroll
    for (int i = 0; i < 4; i++)
#pragma unroll
        for (int j = 0; j < 4; j++) acc[i][j] = vzero;

    const int srow = tid >> 2;
    const int scol = (tid & 3) * 8;
    const u16* Ag = A + (size_t)(m0 + srow) * K + scol;
    const u16* Bg = Bt + (size_t)(n0 + srow) * K + scol;
    for (int k0 = 0; k0 < K; k0 += 32) {
        v8s a0 = *(const v8s*)(Ag + k0);
        v8s a1 = *(const v8s*)(Ag + (size_t)64 * K + k0);
        v8s b0 = *(const v8s*)(Bg + k0);
        v8s b1 = *(const v8s*)(Bg + (size_t)64 * K + k0);
        __syncthreads();
        *(v8s*)&As[tid * 8] = a0;
        *(v8s*)&As[2048 + tid * 8] = a1;
        *(v8s*)&Bs[tid * 8] = b0;
        *(v8s*)&Bs[2048 + tid * 8] = b1;
        __syncthreads();
        v8s af[4], bf[4];
#pragma unroll
        for (int i = 0; i < 4; i++) af[i] = *(const v8s*)&As[(wr * 64 + i * 16 + lm) * 32 + lg * 8];
#pragma unroll
        for (int j = 0; j < 4; j++) bf[j] = *(const v8s*)&Bs[(wc * 64 + j * 16 + lm) * 32 + lg * 8];
#pragma unroll
        for (int i = 0; i < 4; i++)
#pragma unroll
            for (int j = 0; j < 4; j++)
                acc[i][j] = __builtin_amdgcn_mfma_f32_16x16x32_bf16(af[i], bf[j], acc[i][j], 0, 0, 0);
    }

    const int of32 = outf32 ? *outf32 : 0;
#pragma unroll
    for (int i = 0; i < 4; i++) {
#pragma unroll
        for (int r = 0; r < 4; r++) {
            const int row = m0 + wr * 64 + i * 16 + lg * 4 + r;
            const size_t rb = (size_t)row * N;
#pragma unroll
            for (int j = 0; j < 4; j++) {
                const int col = n0 + wc * 64 + j * 16 + lm;
                float v = acc[i][j][r] + b2f(bias[col]);
                if (do_gelu) v = 0.5f * v * (1.0f + erff(v * 0.70710678118f));
                if (res) v += b2f(res[rb + col]);
                if (of32) ((float*)C)[rb + col] = v;
                else ((u16*)C)[rb + col] = f2b(v);
            }
        }
    }
}

// ---------------- QKV GEMM: epilogue scatters head-major Q/K + transposed V ----------------
__global__ __launch_bounds__(256) void gemm_qkv_k(const u16* __restrict__ A,
                                                  const u16* __restrict__ Bt,
                                                  const u16* __restrict__ bias,
                                                  u16* __restrict__ Qh,
                                                  u16* __restrict__ Kh,
                                                  u16* __restrict__ Vth) {
    __shared__ __align__(16) u16 As[128 * 32];
    __shared__ __align__(16) u16 Bs[128 * 32];
    const int tid = threadIdx.x;
    const int wid = tid >> 6, lane = tid & 63;
    const int lg = lane >> 4, lm = lane & 15;
    const int wr = wid >> 1, wc = wid & 1;
    const int m0 = blockIdx.y * 128, n0 = blockIdx.x * 128;
    const int K = 1024;

    const v4f vzero = {0.f, 0.f, 0.f, 0.f};
    v4f acc[4][4];
#pragma unroll
    for (int i = 0; i < 4; i++)
#pragma unroll
        for (int j = 0; j < 4; j++) acc[i][j] = vzero;

    const int srow = tid >> 2;
    const int scol = (tid & 3) * 8;
    const u16* Ag = A + (size_t)(m0 + srow) * K + scol;
    const u16* Bg = Bt + (size_t)(n0 + srow) * K + scol;
    for (int k0 = 0; k0 < K; k0 += 32) {
        v8s a0 = *(const v8s*)(Ag + k0);
        v8s a1 = *(const v8s*)(Ag + (size_t)64 * K + k0);
        v8s b0 = *(const v8s*)(Bg + k0);
        v8s b1 = *(const v8s*)(Bg + (size_t)64 * K + k0);
        __syncthreads();
        *(v8s*)&As[tid * 8] = a0;
        *(v8s*)&As[2048 + tid * 8] = a1;
        *(v8s*)&Bs[tid * 8] = b0;
        *(v8s*)&Bs[2048 + tid * 8] = b1;
        __syncthreads();
        v8s af[4], bf[4];
#pragma unroll
        for (int i = 0; i < 4; i++) af[i] = *(const v8s*)&As[(wr * 64 + i * 16 + lm) * 32 + lg * 8];
#pragma unroll
        for (int j = 0; j < 4; j++) bf[j] = *(const v8s*)&Bs[(wc * 64 + j * 16 + lm) * 32 + lg * 8];
#pragma unroll
        for (int i = 0; i < 4; i++)
#pragma unroll
            for (int j = 0; j < 4; j++)
                acc[i][j] = __builtin_amdgcn_mfma_f32_16x16x32_bf16(af[i], bf[j], acc[i][j], 0, 0, 0);
    }

    const int which = n0 >> 10;                 // 0=q 1=k 2=v
    const int h = ((n0 & 1023) >> 6) + wc;      // head
    if (which < 2) {
        u16* dst = which ? Kh : Qh;
#pragma unroll
        for (int i = 0; i < 4; i++) {
#pragma unroll
            for (int r = 0; r < 4; r++) {
                const int row = m0 + wr * 64 + i * 16 + lg * 4 + r;
                const int b = row >> 11, t = row & 2047;
                const size_t rb = ((size_t)(b * 16 + h) * 2048 + t) * 64;
#pragma unroll
                for (int j = 0; j < 4; j++) {
                    float v = acc[i][j][r] + b2f(bias[n0 + wc * 64 + j * 16 + lm]);
                    dst[rb + j * 16 + lm] = f2b(v);
                }
            }
        }
    } else {
#pragma unroll
        for (int i = 0; i < 4; i++) {
            const int t0 = m0 + wr * 64 + i * 16 + lg * 4;
            const int b = t0 >> 11, tt = t0 & 2047;
#pragma unroll
            for (int j = 0; j < 4; j++) {
                const int d = j * 16 + lm;
                const float bv_ = b2f(bias[n0 + wc * 64 + j * 16 + lm]);
                u16 pk[4];
#pragma unroll
                for (int r = 0; r < 4; r++) pk[r] = f2b(acc[i][j][r] + bv_);
                *(v4s*)&Vth[((size_t)(b * 16 + h) * 64 + d) * 2048 + tt] = *(const v4s*)pk;
            }
        }
    }
}

// ---------------- flash attention v3: wave-autonomous, no __syncthreads ----------------
// One wave per (bh, 16-q-row tile). K/V frags loaded directly from L2-resident
// head-major buffers; per-wave LDS only for the P (C-layout -> A-layout) transpose.
__global__ __launch_bounds__(256, 4) void attn3_k(const u16* __restrict__ Qh,
                                                  const u16* __restrict__ Kh,
                                                  const u16* __restrict__ Vth,
                                                  u16* __restrict__ out) {
    __shared__ __align__(16) u16 Ps[4][16 * 64]; // per-wave P buffer, chunk-swizzled
    const int tid = threadIdx.x;
    const int wid = tid >> 6, lane = tid & 63;
    const int lg = lane >> 4, lm = lane & 15;
    const int wu = blockIdx.x * 4 + wid;          // wave-unit 0..4095
    const int bh = wu >> 7;
    const int idx = wu & 127;
    const int qt = (idx & 1) ? (127 - (idx >> 1)) : (idx >> 1); // pair-balanced
    const int q0 = qt * 16;
    const size_t qkb = (size_t)bh * 2048;
    const u16* Vb = Vth + (size_t)bh * 64 * 2048;
    const v4f vzero = {0.f, 0.f, 0.f, 0.f};
    const float sc = 0.18033688011f; // log2(e)/8

    v8s aq[2];
    {
        const u16* qp = Qh + (qkb + q0 + lm) * 64 + lg * 8;
        aq[0] = *(const v8s*)qp;
        aq[1] = *(const v8s*)(qp + 32);
    }
    float m_run[4], l_run[4];
    v4f o[4];
#pragma unroll
    for (int r = 0; r < 4; r++) { m_run[r] = -1e30f; l_run[r] = 0.f; }
#pragma unroll
    for (int dt = 0; dt < 4; dt++) o[dt] = vzero;

    const int nchunks = (q0 + 79) >> 6;   // keys 0..q0+15 in 64-key chunks
    for (int ci = 0; ci < nchunks; ++ci) {
        const int k0 = ci << 6;
        // ---- QK^T over 64 keys: 4 key-subtiles of 16 ----
        v4f sacc[4];
#pragma unroll
        for (int kt = 0; kt < 4; kt++) {
            const u16* kp = Kh + (qkb + k0 + kt * 16 + lm) * 64 + lg * 8;
            v8s b0 = *(const v8s*)kp;
            v8s b1 = *(const v8s*)(kp + 32);
            sacc[kt] = __builtin_amdgcn_mfma_f32_16x16x32_bf16(aq[0], b0, vzero, 0, 0, 0);
            sacc[kt] = __builtin_amdgcn_mfma_f32_16x16x32_bf16(aq[1], b1, sacc[kt], 0, 0, 0);
        }
        const bool needmask = (k0 + 63 > q0);   // only the diagonal (last) chunk
#pragma unroll
        for (int r = 0; r < 4; r++) {
            float v[4];
#pragma unroll
            for (int kt = 0; kt < 4; kt++) v[kt] = sacc[kt][r] * sc;
            if (needmask) {
                const int qrow = q0 + lg * 4 + r;
#pragma unroll
                for (int kt = 0; kt < 4; kt++)
                    if (k0 + kt * 16 + lm > qrow) v[kt] = -1e30f;
            }
            float mt = fmaxf(fmaxf(v[0], v[1]), fmaxf(v[2], v[3]));
#pragma unroll
            for (int d = 1; d < 16; d <<= 1) mt = fmaxf(mt, __shfl_xor(mt, d, 64));
            const float mn = fmaxf(m_run[r], mt);
            const float al = exp2f(m_run[r] - mn);
            m_run[r] = mn;
            float p[4], rs = 0.f;
#pragma unroll
            for (int kt = 0; kt < 4; kt++) { p[kt] = exp2f(v[kt] - mn); rs += p[kt]; }
#pragma unroll
            for (int d = 1; d < 16; d <<= 1) rs += __shfl_xor(rs, d, 64);
            l_run[r] = l_run[r] * al + rs;
#pragma unroll
            for (int dt = 0; dt < 4; dt++) o[dt][r] *= al;
            const int pr = lg * 4 + r, rx = pr & 7;
#pragma unroll
            for (int kt = 0; kt < 4; kt++) {
                const int chunk = (kt << 1) | (lm >> 3);
                Ps[wid][(pr << 6) + (((chunk ^ rx) << 3) | (lm & 7))] = f2b(p[kt]);
            }
        }
        asm volatile("s_waitcnt lgkmcnt(0)" ::: "memory"); // wave-local round-trip
        v8s ap[2];
#pragma unroll
        for (int kk = 0; kk < 2; kk++)
            ap[kk] = *(const v8s*)&Ps[wid][(lm << 6) + (((kk * 4 + lg) ^ (lm & 7)) << 3)];
        // ---- PV over the same 64 keys ----
#pragma unroll
        for (int dt = 0; dt < 4; dt++) {
            const u16* vp = Vb + (size_t)(dt * 16 + lm) * 2048 + k0 + lg * 8;
            v8s bv0 = *(const v8s*)vp;
            v8s bv1 = *(const v8s*)(vp + 32);
            o[dt] = __builtin_amdgcn_mfma_f32_16x16x32_bf16(ap[0], bv0, o[dt], 0, 0, 0);
            o[dt] = __builtin_amdgcn_mfma_f32_16x16x32_bf16(ap[1], bv1, o[dt], 0, 0, 0);
        }
    }
    const int b = bh >> 4, h = bh & 15;
#pragma unroll
    for (int r = 0; r < 4; r++) {
        const float inv = 1.0f / l_run[r];
        const int qrow = q0 + lg * 4 + r;
        const size_t rowb = ((size_t)b * 2048 + qrow) * 1024 + h * 64;
#pragma unroll
        for (int dt = 0; dt < 4; dt++) out[rowb + dt * 16 + lm] = f2b(o[dt][r] * inv);
    }
}

extern "C" void kernel_launch(void* const* d_in, const int* in_sizes, int n_in,
                              void* d_out, int out_size, void* d_ws, size_t ws_size,
                              hipStream_t stream) {
    const void* x      = d_in[0];
    const void* ln1_g  = d_in[1];
    const void* ln1_b  = d_in[2];
    const void* w_attn = d_in[3];
    const void* b_attn = d_in[4];
    const void* w_proj = d_in[5];
    const void* b_proj = d_in[6];
    const void* ln2_g  = d_in[7];
    const void* ln2_b  = d_in[8];
    const void* w_fc   = d_in[9];
    const void* b_fc   = d_in[10];
    const void* w_fc2  = d_in[11];
    const void* b_fc2  = d_in[12];

    u16* ws = (u16*)d_ws;
    const size_t Mi = 1u << 20;
    u16* xb       = ws;                 // [0,4Mi)
    u16* ln_buf   = ws + 4 * Mi;        // [4,8)
    u16* h_buf    = ws + 8 * Mi;        // [8,12)
    u16* wT_attn  = ws + 12 * Mi;       // [12,15)
    u16* wT_proj  = ws + 15 * Mi;       // [15,16)
    u16* wT_fc    = ws + 16 * Mi;       // [16,20)
    u16* wT_fc2   = ws + 20 * Mi;       // [20,24)
    u16* bb       = ws + 24 * Mi;
    u16* bb_attn = bb, *bb_proj = bb + 4096, *bb_fc = bb + 8192, *bb_fc2 = bb + 12288;
    u16* gsmall   = bb + 16384;
    u16* g_ln1g = gsmall, *g_ln1b = gsmall + 1024, *g_ln2g = gsmall + 2048, *g_ln2b = gsmall + 3072;
    int* flag     = (int*)(bb + 24576);
    u16* Qh       = ws + 25 * Mi;       // [25,29) head-major Q
    u16* Kh       = ws + 29 * Mi;       // [29,33)
    u16* Vth      = ws + 33 * Mi;       // [33,37) V transposed [bh][d][t]
    u16* attn_buf = ws + 37 * Mi;       // [37,41)
    u16* fc_buf   = ws + 25 * Mi;       // [25,41) overlays dead Qh/Kh/Vth/attn_buf
    // total 41 Mi u16 = 82 MiB

    detect_k<<<1, 256, 0, stream>>>(x, flag);

    cvt_k<<<4096, 256, 0, stream>>>(x, xb, 4 * Mi, flag);
    cvt_k<<<12, 256, 0, stream>>>(b_attn, bb_attn, 3072, flag);
    cvt_k<<<4, 256, 0, stream>>>(b_proj, bb_proj, 1024, flag);
    cvt_k<<<16, 256, 0, stream>>>(b_fc, bb_fc, 4096, flag);
    cvt_k<<<4, 256, 0, stream>>>(b_fc2, bb_fc2, 1024, flag);
    cvt_k<<<4, 256, 0, stream>>>(ln1_g, g_ln1g, 1024, flag);
    cvt_k<<<4, 256, 0, stream>>>(ln1_b, g_ln1b, 1024, flag);
    cvt_k<<<4, 256, 0, stream>>>(ln2_g, g_ln2g, 1024, flag);
    cvt_k<<<4, 256, 0, stream>>>(ln2_b, g_ln2b, 1024, flag);

    dim3 tb(32, 8);
    transpose_k<<<dim3(96, 32), tb, 0, stream>>>(w_attn, wT_attn, 1024, 3072, flag);
    transpose_k<<<dim3(32, 32), tb, 0, stream>>>(w_proj, wT_proj, 1024, 1024, flag);
    transpose_k<<<dim3(128, 32), tb, 0, stream>>>(w_fc, wT_fc, 1024, 4096, flag);
    transpose_k<<<dim3(32, 128), tb, 0, stream>>>(w_fc2, wT_fc2, 4096, 1024, flag);

    layernorm_k<<<1024, 256, 0, stream>>>(xb, g_ln1g, g_ln1b, ln_buf);
    gemm_qkv_k<<<dim3(24, 32), 256, 0, stream>>>(ln_buf, wT_attn, bb_attn, Qh, Kh, Vth);
    attn3_k<<<1024, 256, 0, stream>>>(Qh, Kh, Vth, attn_buf);
    gemm_bt_k<<<dim3(8, 32), 256, 0, stream>>>(attn_buf, wT_proj, bb_proj, xb, h_buf,
                                               4096, 1024, 1024, 0, nullptr);
    layernorm_k<<<1024, 256, 0, stream>>>(h_buf, g_ln2g, g_ln2b, ln_buf);
    gemm_bt_k<<<dim3(32, 32), 256, 0, stream>>>(ln_buf, wT_fc, bb_fc, nullptr, fc_buf,
                                                4096, 4096, 1024, 1, nullptr);
    gemm_bt_k<<<dim3(8, 32), 256, 0, stream>>>(fc_buf, wT_fc2, bb_fc2, h_buf, d_out,
                                               4096, 1024, 4096, 0, flag);
}

// Round 6
// 555.953 us; speedup vs baseline: 1.1512x; 1.0611x over previous
//
#include <hip/hip_runtime.h>

typedef unsigned short u16;
typedef unsigned int u32;
typedef short v8s __attribute__((ext_vector_type(8)));
typedef short v4s __attribute__((ext_vector_type(4)));
typedef float v4f __attribute__((ext_vector_type(4)));

__device__ __forceinline__ float b2f(u16 v) {
    return __uint_as_float(((u32)v) << 16);
}
__device__ __forceinline__ u16 f2b(float f) {
    u32 u = __float_as_uint(f);
    return (u16)((u + 0x7FFFu + ((u >> 16) & 1u)) >> 16);
}

// ---------------- dtype detect: bf16 vs f32 reinterpretation ----------------
__global__ void detect_k(const void* x, int* flag) {
    __shared__ int cnt;
    if (threadIdx.x == 0) cnt = 0;
    __syncthreads();
    const u16* p = (const u16*)x;
    int bad = 0;
    for (int i = threadIdx.x; i < 4096; i += 256) {
        int e = (p[i] >> 7) & 0xFF;
        if (e != 0 && (e < 100 || e > 140)) bad++;
    }
    atomicAdd(&cnt, bad);
    __syncthreads();
    if (threadIdx.x == 0) *flag = (cnt > 256) ? 1 : 0;
}

// ---------------- convert to bf16 (grid-stride) ----------------
__global__ void cvt_k(const void* __restrict__ src, u16* __restrict__ dst, int n,
                      const int* __restrict__ flag) {
    const int isf32 = *flag;
    for (int i = blockIdx.x * 256 + threadIdx.x; i < n; i += gridDim.x * 256)
        dst[i] = isf32 ? f2b(((const float*)src)[i]) : ((const u16*)src)[i];
}

// ---------------- transpose+convert: in[R][C] -> out[C][R] bf16 ----------------
__global__ void transpose_k(const void* __restrict__ in, u16* __restrict__ out, int R, int C,
                            const int* __restrict__ flag) {
    __shared__ u16 t[32][33];
    const int isf32 = *flag;
    const int c0 = blockIdx.x * 32, r0 = blockIdx.y * 32;
    for (int i = threadIdx.y; i < 32; i += 8) {
        size_t idx = (size_t)(r0 + i) * C + c0 + threadIdx.x;
        t[i][threadIdx.x] = isf32 ? f2b(((const float*)in)[idx]) : ((const u16*)in)[idx];
    }
    __syncthreads();
    for (int i = threadIdx.y; i < 32; i += 8)
        out[(size_t)(c0 + i) * R + r0 + threadIdx.x] = t[threadIdx.x][i];
}

// ---------------- layernorm: one wave per 1024-elem row (bf16 in ws) ----------------
__global__ __launch_bounds__(256) void layernorm_k(const u16* __restrict__ x,
                                                   const u16* __restrict__ g,
                                                   const u16* __restrict__ bta,
                                                   u16* __restrict__ out) {
    const int wid = threadIdx.x >> 6, lane = threadIdx.x & 63;
    const size_t row = (size_t)blockIdx.x * 4 + wid;
    const u16* xr = x + row * 1024 + lane * 16;
    u16 v[16];
    *(uint4*)&v[0] = *(const uint4*)xr;
    *(uint4*)&v[8] = *(const uint4*)(xr + 8);
    float f[16], s = 0.f, sq = 0.f;
#pragma unroll
    for (int i = 0; i < 16; i++) { f[i] = b2f(v[i]); s += f[i]; sq += f[i] * f[i]; }
#pragma unroll
    for (int d = 1; d < 64; d <<= 1) { s += __shfl_xor(s, d, 64); sq += __shfl_xor(sq, d, 64); }
    const float mean = s * (1.f / 1024.f);
    const float var = sq * (1.f / 1024.f) - mean * mean;
    const float rstd = rsqrtf(var + 1e-5f);
    u16 gv[16], bv[16];
    *(uint4*)&gv[0] = *(const uint4*)(g + lane * 16);
    *(uint4*)&gv[8] = *(const uint4*)(g + lane * 16 + 8);
    *(uint4*)&bv[0] = *(const uint4*)(bta + lane * 16);
    *(uint4*)&bv[8] = *(const uint4*)(bta + lane * 16 + 8);
    u16 ov[16];
#pragma unroll
    for (int i = 0; i < 16; i++) ov[i] = f2b((f[i] - mean) * rstd * b2f(gv[i]) + b2f(bv[i]));
    u16* orow = out + row * 1024 + lane * 16;
    *(uint4*)orow = *(uint4*)&ov[0];
    *(uint4*)(orow + 8) = *(uint4*)&ov[8];
}

// ---------------- generic GEMM: C[M][N] = A @ Bt^T + bias (+gelu) (+res) ----------------
__global__ __launch_bounds__(256) void gemm_bt_k(const u16* __restrict__ A,
                                                 const u16* __restrict__ Bt,
                                                 const u16* __restrict__ bias,
                                                 const u16* __restrict__ res,
                                                 void* __restrict__ C,
                                                 int M, int N, int K, int do_gelu,
                                                 const int* __restrict__ outf32) {
    __shared__ __align__(16) u16 As[128 * 32];
    __shared__ __align__(16) u16 Bs[128 * 32];
    const int tid = threadIdx.x;
    const int wid = tid >> 6, lane = tid & 63;
    const int lg = lane >> 4, lm = lane & 15;
    const int wr = wid >> 1, wc = wid & 1;
    const int m0 = blockIdx.y * 128, n0 = blockIdx.x * 128;

    const v4f vzero = {0.f, 0.f, 0.f, 0.f};
    v4f acc[4][4];
#pragma unroll
    for (int i = 0; i < 4; i++)
#pragma unroll
        for (int j = 0; j < 4; j++) acc[i][j] = vzero;

    const int srow = tid >> 2;
    const int scol = (tid & 3) * 8;
    const u16* Ag = A + (size_t)(m0 + srow) * K + scol;
    const u16* Bg = Bt + (size_t)(n0 + srow) * K + scol;
    for (int k0 = 0; k0 < K; k0 += 32) {
        v8s a0 = *(const v8s*)(Ag + k0);
        v8s a1 = *(const v8s*)(Ag + (size_t)64 * K + k0);
        v8s b0 = *(const v8s*)(Bg + k0);
        v8s b1 = *(const v8s*)(Bg + (size_t)64 * K + k0);
        __syncthreads();
        *(v8s*)&As[tid * 8] = a0;
        *(v8s*)&As[2048 + tid * 8] = a1;
        *(v8s*)&Bs[tid * 8] = b0;
        *(v8s*)&Bs[2048 + tid * 8] = b1;
        __syncthreads();
        v8s af[4], bf[4];
#pragma unroll
        for (int i = 0; i < 4; i++) af[i] = *(const v8s*)&As[(wr * 64 + i * 16 + lm) * 32 + lg * 8];
#pragma unroll
        for (int j = 0; j < 4; j++) bf[j] = *(const v8s*)&Bs[(wc * 64 + j * 16 + lm) * 32 + lg * 8];
#pragma unroll
        for (int i = 0; i < 4; i++)
#pragma unroll
            for (int j = 0; j < 4; j++)
                acc[i][j] = __builtin_amdgcn_mfma_f32_16x16x32_bf16(af[i], bf[j], acc[i][j], 0, 0, 0);
    }

    const int of32 = outf32 ? *outf32 : 0;
#pragma unroll
    for (int i = 0; i < 4; i++) {
#pragma unroll
        for (int r = 0; r < 4; r++) {
            const int row = m0 + wr * 64 + i * 16 + lg * 4 + r;
            const size_t rb = (size_t)row * N;
#pragma unroll
            for (int j = 0; j < 4; j++) {
                const int col = n0 + wc * 64 + j * 16 + lm;
                float v = acc[i][j][r] + b2f(bias[col]);
                if (do_gelu) v = 0.5f * v * (1.0f + erff(v * 0.70710678118f));
                if (res) v += b2f(res[rb + col]);
                if (of32) ((float*)C)[rb + col] = v;
                else ((u16*)C)[rb + col] = f2b(v);
            }
        }
    }
}

// ---------------- QKV GEMM: epilogue scatters head-major Q/K + permuted-transposed V ----------------
// V^T stored with per-32-key permutation pos(w) = 8*((w&15)>>2) + 4*(w>>4) + (w&3)
// so attention's PV B-frag (P^T in registers) needs NO cross-lane transpose.
__global__ __launch_bounds__(256) void gemm_qkv_k(const u16* __restrict__ A,
                                                  const u16* __restrict__ Bt,
                                                  const u16* __restrict__ bias,
                                                  u16* __restrict__ Qh,
                                                  u16* __restrict__ Kh,
                                                  u16* __restrict__ Vth) {
    __shared__ __align__(16) u16 As[128 * 32];
    __shared__ __align__(16) u16 Bs[128 * 32];
    const int tid = threadIdx.x;
    const int wid = tid >> 6, lane = tid & 63;
    const int lg = lane >> 4, lm = lane & 15;
    const int wr = wid >> 1, wc = wid & 1;
    const int m0 = blockIdx.y * 128, n0 = blockIdx.x * 128;
    const int K = 1024;

    const v4f vzero = {0.f, 0.f, 0.f, 0.f};
    v4f acc[4][4];
#pragma unroll
    for (int i = 0; i < 4; i++)
#pragma unroll
        for (int j = 0; j < 4; j++) acc[i][j] = vzero;

    const int srow = tid >> 2;
    const int scol = (tid & 3) * 8;
    const u16* Ag = A + (size_t)(m0 + srow) * K + scol;
    const u16* Bg = Bt + (size_t)(n0 + srow) * K + scol;
    for (int k0 = 0; k0 < K; k0 += 32) {
        v8s a0 = *(const v8s*)(Ag + k0);
        v8s a1 = *(const v8s*)(Ag + (size_t)64 * K + k0);
        v8s b0 = *(const v8s*)(Bg + k0);
        v8s b1 = *(const v8s*)(Bg + (size_t)64 * K + k0);
        __syncthreads();
        *(v8s*)&As[tid * 8] = a0;
        *(v8s*)&As[2048 + tid * 8] = a1;
        *(v8s*)&Bs[tid * 8] = b0;
        *(v8s*)&Bs[2048 + tid * 8] = b1;
        __syncthreads();
        v8s af[4], bf[4];
#pragma unroll
        for (int i = 0; i < 4; i++) af[i] = *(const v8s*)&As[(wr * 64 + i * 16 + lm) * 32 + lg * 8];
#pragma unroll
        for (int j = 0; j < 4; j++) bf[j] = *(const v8s*)&Bs[(wc * 64 + j * 16 + lm) * 32 + lg * 8];
#pragma unroll
        for (int i = 0; i < 4; i++)
#pragma unroll
            for (int j = 0; j < 4; j++)
                acc[i][j] = __builtin_amdgcn_mfma_f32_16x16x32_bf16(af[i], bf[j], acc[i][j], 0, 0, 0);
    }

    const int which = n0 >> 10;                 // 0=q 1=k 2=v
    const int h = ((n0 & 1023) >> 6) + wc;      // head
    if (which < 2) {
        u16* dst = which ? Kh : Qh;
#pragma unroll
        for (int i = 0; i < 4; i++) {
#pragma unroll
            for (int r = 0; r < 4; r++) {
                const int row = m0 + wr * 64 + i * 16 + lg * 4 + r;
                const int b = row >> 11, t = row & 2047;
                const size_t rb = ((size_t)(b * 16 + h) * 2048 + t) * 64;
#pragma unroll
                for (int j = 0; j < 4; j++) {
                    float v = acc[i][j][r] + b2f(bias[n0 + wc * 64 + j * 16 + lm]);
                    dst[rb + j * 16 + lm] = f2b(v);
                }
            }
        }
    } else {
#pragma unroll
        for (int i = 0; i < 4; i++) {
            const int t0 = m0 + wr * 64 + i * 16 + lg * 4;
            const int b = t0 >> 11, tt = t0 & 2047;
            // permuted position within the 32-key block (tt % 4 == 0 here)
            const int w = tt & 31;
            const int pos = (tt & ~31) + ((w & 15) >> 2) * 8 + ((w >> 4) & 1) * 4;
#pragma unroll
            for (int j = 0; j < 4; j++) {
                const int d = j * 16 + lm;
                const float bv_ = b2f(bias[n0 + wc * 64 + j * 16 + lm]);
                u16 pk[4];
#pragma unroll
                for (int r = 0; r < 4; r++) pk[r] = f2b(acc[i][j][r] + bv_);
                *(v4s*)&Vth[((size_t)(b * 16 + h) * 64 + d) * 2048 + pos] = *(const v4s*)pk;
            }
        }
    }
}

// ---------------- flash attention v4: transposed-S orientation, zero LDS ----------------
// One wave per (bh, 16-q-row tile). S^T = mfma(Kfrag, Qfrag): qrow = lane&15 ->
// per-lane scalar softmax state, 2 shuffle rounds per reduction, and P^T feeds
// PV (O^T = V^T P^T) directly from registers via the V permuted layout.
__global__ __launch_bounds__(256, 4) void attn4_k(const u16* __restrict__ Qh,
                                                  const u16* __restrict__ Kh,
                                                  const u16* __restrict__ Vth,
                                                  u16* __restrict__ out) {
    const int tid = threadIdx.x;
    const int wid = tid >> 6, lane = tid & 63;
    const int lg = lane >> 4, lm = lane & 15;
    const int wu = blockIdx.x * 4 + wid;          // wave-unit 0..4095
    const int bh = wu >> 7;
    const int idx = wu & 127;
    const int qt = (idx & 1) ? (127 - (idx >> 1)) : (idx >> 1); // pair-balanced
    const int q0 = qt * 16;
    const int qrow_l = q0 + lm;                   // this lane's softmax row
    const size_t qkb = (size_t)bh * 2048;
    const u16* Vb = Vth + (size_t)bh * 64 * 2048;
    const v4f vzero = {0.f, 0.f, 0.f, 0.f};
    const float sc = 0.18033688011f; // log2(e)/8

    v8s aq[2];
    {
        const u16* qp = Qh + (qkb + q0 + lm) * 64 + lg * 8;
        aq[0] = *(const v8s*)qp;
        aq[1] = *(const v8s*)(qp + 32);
    }
    float m_run = -1e30f, l_run = 0.f;
    v4f o[4];   // O^T tiles: lane holds qrow=lm, d = dt*16 + lg*4 + r
#pragma unroll
    for (int dt = 0; dt < 4; dt++) o[dt] = vzero;

    const int nchunks = (q0 + 79) >> 6;   // keys 0..q0+15 in 64-key chunks
    for (int ci = 0; ci < nchunks; ++ci) {
        const int k0 = ci << 6;
        // ---- S^T = K·Q^T over 64 keys: 4 key-subtiles of 16 ----
        v4f sacc[4];
#pragma unroll
        for (int kt = 0; kt < 4; kt++) {
            const u16* kp = Kh + (qkb + k0 + kt * 16 + lm) * 64 + lg * 8;
            v8s k0f = *(const v8s*)kp;
            v8s k1f = *(const v8s*)(kp + 32);
            sacc[kt] = __builtin_amdgcn_mfma_f32_16x16x32_bf16(k0f, aq[0], vzero, 0, 0, 0);
            sacc[kt] = __builtin_amdgcn_mfma_f32_16x16x32_bf16(k1f, aq[1], sacc[kt], 0, 0, 0);
        }
        float vv[4][4];
#pragma unroll
        for (int kt = 0; kt < 4; kt++)
#pragma unroll
            for (int r = 0; r < 4; r++) vv[kt][r] = sacc[kt][r] * sc;
        if (k0 + 63 > q0) {   // diagonal chunk only (wave-uniform branch)
#pragma unroll
            for (int kt = 0; kt < 4; kt++)
#pragma unroll
                for (int r = 0; r < 4; r++)
                    if (k0 + kt * 16 + lg * 4 + r > qrow_l) vv[kt][r] = -1e30f;
        }
        float mt = -1e30f;
#pragma unroll
        for (int kt = 0; kt < 4; kt++)
#pragma unroll
            for (int r = 0; r < 4; r++) mt = fmaxf(mt, vv[kt][r]);
        mt = fmaxf(mt, __shfl_xor(mt, 16, 64));
        mt = fmaxf(mt, __shfl_xor(mt, 32, 64));
        const float mn = fmaxf(m_run, mt);
        const float al = exp2f(m_run - mn);
        m_run = mn;
        float rs = 0.f;
        v8s B0, B1;
#pragma unroll
        for (int kt = 0; kt < 4; kt++)
#pragma unroll
            for (int r = 0; r < 4; r++) {
                float p = exp2f(vv[kt][r] - mn);
                rs += p;
                const u16 pb = f2b(p);
                if (kt < 2) B0[kt * 4 + r] = (short)pb;
                else        B1[(kt - 2) * 4 + r] = (short)pb;
            }
        rs += __shfl_xor(rs, 16, 64);
        rs += __shfl_xor(rs, 32, 64);
        l_run = l_run * al + rs;
#pragma unroll
        for (int dt = 0; dt < 4; dt++) o[dt] *= al;
        // ---- O^T += V^T P^T over the same 64 keys (2 permuted 32-key blocks) ----
#pragma unroll
        for (int dt = 0; dt < 4; dt++) {
            const u16* vp = Vb + (size_t)(dt * 16 + lm) * 2048 + k0 + lg * 8;
            v8s va0 = *(const v8s*)vp;
            v8s va1 = *(const v8s*)(vp + 32);
            o[dt] = __builtin_amdgcn_mfma_f32_16x16x32_bf16(va0, B0, o[dt], 0, 0, 0);
            o[dt] = __builtin_amdgcn_mfma_f32_16x16x32_bf16(va1, B1, o[dt], 0, 0, 0);
        }
    }
    const int b = bh >> 4, h = bh & 15;
    const float inv = 1.0f / l_run;
    const size_t rowb = ((size_t)b * 2048 + q0 + lm) * 1024 + h * 64;
#pragma unroll
    for (int dt = 0; dt < 4; dt++) {
        u16 pk[4];
#pragma unroll
        for (int r = 0; r < 4; r++) pk[r] = f2b(o[dt][r] * inv);
        *(v4s*)&out[rowb + dt * 16 + lg * 4] = *(const v4s*)pk;
    }
}

extern "C" void kernel_launch(void* const* d_in, const int* in_sizes, int n_in,
                              void* d_out, int out_size, void* d_ws, size_t ws_size,
                              hipStream_t stream) {
    const void* x      = d_in[0];
    const void* ln1_g  = d_in[1];
    const void* ln1_b  = d_in[2];
    const void* w_attn = d_in[3];
    const void* b_attn = d_in[4];
    const void* w_proj = d_in[5];
    const void* b_proj = d_in[6];
    const void* ln2_g  = d_in[7];
    const void* ln2_b  = d_in[8];
    const void* w_fc   = d_in[9];
    const void* b_fc   = d_in[10];
    const void* w_fc2  = d_in[11];
    const void* b_fc2  = d_in[12];

    u16* ws = (u16*)d_ws;
    const size_t Mi = 1u << 20;
    u16* xb       = ws;                 // [0,4Mi)
    u16* ln_buf   = ws + 4 * Mi;        // [4,8)
    u16* h_buf    = ws + 8 * Mi;        // [8,12)
    u16* wT_attn  = ws + 12 * Mi;       // [12,15)
    u16* wT_proj  = ws + 15 * Mi;       // [15,16)
    u16* wT_fc    = ws + 16 * Mi;       // [16,20)
    u16* wT_fc2   = ws + 20 * Mi;       // [20,24)
    u16* bb       = ws + 24 * Mi;
    u16* bb_attn = bb, *bb_proj = bb + 4096, *bb_fc = bb + 8192, *bb_fc2 = bb + 12288;
    u16* gsmall   = bb + 16384;
    u16* g_ln1g = gsmall, *g_ln1b = gsmall + 1024, *g_ln2g = gsmall + 2048, *g_ln2b = gsmall + 3072;
    int* flag     = (int*)(bb + 24576);
    u16* Qh       = ws + 25 * Mi;       // [25,29) head-major Q
    u16* Kh       = ws + 29 * Mi;       // [29,33)
    u16* Vth      = ws + 33 * Mi;       // [33,37) V^T permuted [bh][d][pos(t)]
    u16* attn_buf = ws + 37 * Mi;       // [37,41)
    u16* fc_buf   = ws + 25 * Mi;       // [25,41) overlays dead Qh/Kh/Vth/attn_buf
    // total 41 Mi u16 = 82 MiB

    detect_k<<<1, 256, 0, stream>>>(x, flag);

    cvt_k<<<4096, 256, 0, stream>>>(x, xb, 4 * Mi, flag);
    cvt_k<<<12, 256, 0, stream>>>(b_attn, bb_attn, 3072, flag);
    cvt_k<<<4, 256, 0, stream>>>(b_proj, bb_proj, 1024, flag);
    cvt_k<<<16, 256, 0, stream>>>(b_fc, bb_fc, 4096, flag);
    cvt_k<<<4, 256, 0, stream>>>(b_fc2, bb_fc2, 1024, flag);
    cvt_k<<<4, 256, 0, stream>>>(ln1_g, g_ln1g, 1024, flag);
    cvt_k<<<4, 256, 0, stream>>>(ln1_b, g_ln1b, 1024, flag);
    cvt_k<<<4, 256, 0, stream>>>(ln2_g, g_ln2g, 1024, flag);
    cvt_k<<<4, 256, 0, stream>>>(ln2_b, g_ln2b, 1024, flag);

    dim3 tb(32, 8);
    transpose_k<<<dim3(96, 32), tb, 0, stream>>>(w_attn, wT_attn, 1024, 3072, flag);
    transpose_k<<<dim3(32, 32), tb, 0, stream>>>(w_proj, wT_proj, 1024, 1024, flag);
    transpose_k<<<dim3(128, 32), tb, 0, stream>>>(w_fc, wT_fc, 1024, 4096, flag);
    transpose_k<<<dim3(32, 128), tb, 0, stream>>>(w_fc2, wT_fc2, 4096, 1024, flag);

    layernorm_k<<<1024, 256, 0, stream>>>(xb, g_ln1g, g_ln1b, ln_buf);
    gemm_qkv_k<<<dim3(24, 32), 256, 0, stream>>>(ln_buf, wT_attn, bb_attn, Qh, Kh, Vth);
    attn4_k<<<1024, 256, 0, stream>>>(Qh, Kh, Vth, attn_buf);
    gemm_bt_k<<<dim3(8, 32), 256, 0, stream>>>(attn_buf, wT_proj, bb_proj, xb, h_buf,
                                               4096, 1024, 1024, 0, nullptr);
    layernorm_k<<<1024, 256, 0, stream>>>(h_buf, g_ln2g, g_ln2b, ln_buf);
    gemm_bt_k<<<dim3(32, 32), 256, 0, stream>>>(ln_buf, wT_fc, bb_fc, nullptr, fc_buf,
                                                4096, 4096, 1024, 1, nullptr);
    gemm_bt_k<<<dim3(8, 32), 256, 0, stream>>>(fc_buf, wT_fc2, bb_fc2, h_buf, d_out,
                                               4096, 1024, 4096, 0, flag);
}

// Round 7
// 545.045 us; speedup vs baseline: 1.1742x; 1.0200x over previous
//
#include <hip/hip_runtime.h>

typedef unsigned short u16;
typedef unsigned int u32;
typedef short v8s __attribute__((ext_vector_type(8)));
typedef short v4s __attribute__((ext_vector_type(4)));
typedef float v4f __attribute__((ext_vector_type(4)));

__device__ __forceinline__ float b2f(u16 v) {
    return __uint_as_float(((u32)v) << 16);
}
__device__ __forceinline__ u16 f2b(float f) {
    u32 u = __float_as_uint(f);
    return (u16)((u + 0x7FFFu + ((u >> 16) & 1u)) >> 16);
}

// ---------------- dtype detect: bf16 vs f32 reinterpretation ----------------
__global__ void detect_k(const void* x, int* flag) {
    __shared__ int cnt;
    if (threadIdx.x == 0) cnt = 0;
    __syncthreads();
    const u16* p = (const u16*)x;
    int bad = 0;
    for (int i = threadIdx.x; i < 4096; i += 256) {
        int e = (p[i] >> 7) & 0xFF;
        if (e != 0 && (e < 100 || e > 140)) bad++;
    }
    atomicAdd(&cnt, bad);
    __syncthreads();
    if (threadIdx.x == 0) *flag = (cnt > 256) ? 1 : 0;
}

// ---------------- convert to bf16 (grid-stride) ----------------
__global__ void cvt_k(const void* __restrict__ src, u16* __restrict__ dst, int n,
                      const int* __restrict__ flag) {
    const int isf32 = *flag;
    for (int i = blockIdx.x * 256 + threadIdx.x; i < n; i += gridDim.x * 256)
        dst[i] = isf32 ? f2b(((const float*)src)[i]) : ((const u16*)src)[i];
}

// ---------------- fused small-tensor convert (biases + ln params) ----------------
struct P8 { const void* p[8]; };
__global__ void cvt_small_k(P8 src, u16* __restrict__ bb, const int* __restrict__ flag) {
    const int isf32 = *flag;
    // segments: b_attn, b_proj, b_fc, b_fc2, ln1_g, ln1_b, ln2_g, ln2_b
    const int len[8] = {3072, 1024, 4096, 1024, 1024, 1024, 1024, 1024};
    const int doff[8] = {0, 4096, 8192, 12288, 16384, 17408, 18432, 19456};
    int gi = blockIdx.x * 256 + threadIdx.x;   // 0..13311
    int seg = 0, off = gi;
    while (seg < 7 && off >= len[seg]) { off -= len[seg]; seg++; }
    if (off < len[seg]) {
        const void* s = src.p[seg];
        bb[doff[seg] + off] = isf32 ? f2b(((const float*)s)[off]) : ((const u16*)s)[off];
    }
}

// ---------------- transpose+convert: in[R][C] -> out[C][R] bf16 ----------------
__global__ void transpose_k(const void* __restrict__ in, u16* __restrict__ out, int R, int C,
                            const int* __restrict__ flag) {
    __shared__ u16 t[32][33];
    const int isf32 = *flag;
    const int c0 = blockIdx.x * 32, r0 = blockIdx.y * 32;
    for (int i = threadIdx.y; i < 32; i += 8) {
        size_t idx = (size_t)(r0 + i) * C + c0 + threadIdx.x;
        t[i][threadIdx.x] = isf32 ? f2b(((const float*)in)[idx]) : ((const u16*)in)[idx];
    }
    __syncthreads();
    for (int i = threadIdx.y; i < 32; i += 8)
        out[(size_t)(c0 + i) * R + r0 + threadIdx.x] = t[threadIdx.x][i];
}

// ---------------- layernorm: one wave per 1024-elem row (bf16 in ws) ----------------
__global__ __launch_bounds__(256) void layernorm_k(const u16* __restrict__ x,
                                                   const u16* __restrict__ g,
                                                   const u16* __restrict__ bta,
                                                   u16* __restrict__ out) {
    const int wid = threadIdx.x >> 6, lane = threadIdx.x & 63;
    const size_t row = (size_t)blockIdx.x * 4 + wid;
    const u16* xr = x + row * 1024 + lane * 16;
    u16 v[16];
    *(uint4*)&v[0] = *(const uint4*)xr;
    *(uint4*)&v[8] = *(const uint4*)(xr + 8);
    float f[16], s = 0.f, sq = 0.f;
#pragma unroll
    for (int i = 0; i < 16; i++) { f[i] = b2f(v[i]); s += f[i]; sq += f[i] * f[i]; }
#pragma unroll
    for (int d = 1; d < 64; d <<= 1) { s += __shfl_xor(s, d, 64); sq += __shfl_xor(sq, d, 64); }
    const float mean = s * (1.f / 1024.f);
    const float var = sq * (1.f / 1024.f) - mean * mean;
    const float rstd = rsqrtf(var + 1e-5f);
    u16 gv[16], bv[16];
    *(uint4*)&gv[0] = *(const uint4*)(g + lane * 16);
    *(uint4*)&gv[8] = *(const uint4*)(g + lane * 16 + 8);
    *(uint4*)&bv[0] = *(const uint4*)(bta + lane * 16);
    *(uint4*)&bv[8] = *(const uint4*)(bta + lane * 16 + 8);
    u16 ov[16];
#pragma unroll
    for (int i = 0; i < 16; i++) ov[i] = f2b((f[i] - mean) * rstd * b2f(gv[i]) + b2f(bv[i]));
    u16* orow = out + row * 1024 + lane * 16;
    *(uint4*)orow = *(uint4*)&ov[0];
    *(uint4*)(orow + 8) = *(uint4*)&ov[8];
}

// ---------------- generic GEMM: C[M][N] = A @ Bt^T + bias (+gelu) (+res) ----------------
__global__ __launch_bounds__(256) void gemm_bt_k(const u16* __restrict__ A,
                                                 const u16* __restrict__ Bt,
                                                 const u16* __restrict__ bias,
                                                 const u16* __restrict__ res,
                                                 void* __restrict__ C,
                                                 int M, int N, int K, int do_gelu,
                                                 const int* __restrict__ outf32) {
    __shared__ __align__(16) u16 As[128 * 32];
    __shared__ __align__(16) u16 Bs[128 * 32];
    const int tid = threadIdx.x;
    const int wid = tid >> 6, lane = tid & 63;
    const int lg = lane >> 4, lm = lane & 15;
    const int wr = wid >> 1, wc = wid & 1;
    const int m0 = blockIdx.y * 128, n0 = blockIdx.x * 128;

    const v4f vzero = {0.f, 0.f, 0.f, 0.f};
    v4f acc[4][4];
#pragma unroll
    for (int i = 0; i < 4; i++)
#pragma unroll
        for (int j = 0; j < 4; j++) acc[i][j] = vzero;

    const int srow = tid >> 2;
    const int scol = (tid & 3) * 8;
    const u16* Ag = A + (size_t)(m0 + srow) * K + scol;
    const u16* Bg = Bt + (size_t)(n0 + srow) * K + scol;
    for (int k0 = 0; k0 < K; k0 += 32) {
        v8s a0 = *(const v8s*)(Ag + k0);
        v8s a1 = *(const v8s*)(Ag + (size_t)64 * K + k0);
        v8s b0 = *(const v8s*)(Bg + k0);
        v8s b1 = *(const v8s*)(Bg + (size_t)64 * K + k0);
        __syncthreads();
        *(v8s*)&As[tid * 8] = a0;
        *(v8s*)&As[2048 + tid * 8] = a1;
        *(v8s*)&Bs[tid * 8] = b0;
        *(v8s*)&Bs[2048 + tid * 8] = b1;
        __syncthreads();
        v8s af[4], bf[4];
#pragma unroll
        for (int i = 0; i < 4; i++) af[i] = *(const v8s*)&As[(wr * 64 + i * 16 + lm) * 32 + lg * 8];
#pragma unroll
        for (int j = 0; j < 4; j++) bf[j] = *(const v8s*)&Bs[(wc * 64 + j * 16 + lm) * 32 + lg * 8];
#pragma unroll
        for (int i = 0; i < 4; i++)
#pragma unroll
            for (int j = 0; j < 4; j++)
                acc[i][j] = __builtin_amdgcn_mfma_f32_16x16x32_bf16(af[i], bf[j], acc[i][j], 0, 0, 0);
    }

    const int of32 = outf32 ? *outf32 : 0;
#pragma unroll
    for (int i = 0; i < 4; i++) {
#pragma unroll
        for (int r = 0; r < 4; r++) {
            const int row = m0 + wr * 64 + i * 16 + lg * 4 + r;
            const size_t rb = (size_t)row * N;
#pragma unroll
            for (int j = 0; j < 4; j++) {
                const int col = n0 + wc * 64 + j * 16 + lm;
                float v = acc[i][j][r] + b2f(bias[col]);
                if (do_gelu) v = 0.5f * v * (1.0f + erff(v * 0.70710678118f));
                if (res) v += b2f(res[rb + col]);
                if (of32) ((float*)C)[rb + col] = v;
                else ((u16*)C)[rb + col] = f2b(v);
            }
        }
    }
}

// ---------------- QKV GEMM: epilogue scatters head-major Q/K + permuted-transposed V ----------------
// V^T stored with per-32-key permutation pos(w) = 8*((w&15)>>2) + 4*(w>>4) + (w&3)
// so attention's PV B-frag (P^T in registers) needs NO cross-lane transpose.
__global__ __launch_bounds__(256) void gemm_qkv_k(const u16* __restrict__ A,
                                                  const u16* __restrict__ Bt,
                                                  const u16* __restrict__ bias,
                                                  u16* __restrict__ Qh,
                                                  u16* __restrict__ Kh,
                                                  u16* __restrict__ Vth) {
    __shared__ __align__(16) u16 As[128 * 32];
    __shared__ __align__(16) u16 Bs[128 * 32];
    const int tid = threadIdx.x;
    const int wid = tid >> 6, lane = tid & 63;
    const int lg = lane >> 4, lm = lane & 15;
    const int wr = wid >> 1, wc = wid & 1;
    const int m0 = blockIdx.y * 128, n0 = blockIdx.x * 128;
    const int K = 1024;

    const v4f vzero = {0.f, 0.f, 0.f, 0.f};
    v4f acc[4][4];
#pragma unroll
    for (int i = 0; i < 4; i++)
#pragma unroll
        for (int j = 0; j < 4; j++) acc[i][j] = vzero;

    const int srow = tid >> 2;
    const int scol = (tid & 3) * 8;
    const u16* Ag = A + (size_t)(m0 + srow) * K + scol;
    const u16* Bg = Bt + (size_t)(n0 + srow) * K + scol;
    for (int k0 = 0; k0 < K; k0 += 32) {
        v8s a0 = *(const v8s*)(Ag + k0);
        v8s a1 = *(const v8s*)(Ag + (size_t)64 * K + k0);
        v8s b0 = *(const v8s*)(Bg + k0);
        v8s b1 = *(const v8s*)(Bg + (size_t)64 * K + k0);
        __syncthreads();
        *(v8s*)&As[tid * 8] = a0;
        *(v8s*)&As[2048 + tid * 8] = a1;
        *(v8s*)&Bs[tid * 8] = b0;
        *(v8s*)&Bs[2048 + tid * 8] = b1;
        __syncthreads();
        v8s af[4], bf[4];
#pragma unroll
        for (int i = 0; i < 4; i++) af[i] = *(const v8s*)&As[(wr * 64 + i * 16 + lm) * 32 + lg * 8];
#pragma unroll
        for (int j = 0; j < 4; j++) bf[j] = *(const v8s*)&Bs[(wc * 64 + j * 16 + lm) * 32 + lg * 8];
#pragma unroll
        for (int i = 0; i < 4; i++)
#pragma unroll
            for (int j = 0; j < 4; j++)
                acc[i][j] = __builtin_amdgcn_mfma_f32_16x16x32_bf16(af[i], bf[j], acc[i][j], 0, 0, 0);
    }

    const int which = n0 >> 10;                 // 0=q 1=k 2=v
    const int h = ((n0 & 1023) >> 6) + wc;      // head
    if (which < 2) {
        u16* dst = which ? Kh : Qh;
#pragma unroll
        for (int i = 0; i < 4; i++) {
#pragma unroll
            for (int r = 0; r < 4; r++) {
                const int row = m0 + wr * 64 + i * 16 + lg * 4 + r;
                const int b = row >> 11, t = row & 2047;
                const size_t rb = ((size_t)(b * 16 + h) * 2048 + t) * 64;
#pragma unroll
                for (int j = 0; j < 4; j++) {
                    float v = acc[i][j][r] + b2f(bias[n0 + wc * 64 + j * 16 + lm]);
                    dst[rb + j * 16 + lm] = f2b(v);
                }
            }
        }
    } else {
#pragma unroll
        for (int i = 0; i < 4; i++) {
            const int t0 = m0 + wr * 64 + i * 16 + lg * 4;
            const int b = t0 >> 11, tt = t0 & 2047;
            // permuted position within the 32-key block (tt % 4 == 0 here)
            const int w = tt & 31;
            const int pos = (tt & ~31) + ((w & 15) >> 2) * 8 + ((w >> 4) & 1) * 4;
#pragma unroll
            for (int j = 0; j < 4; j++) {
                const int d = j * 16 + lm;
                const float bv_ = b2f(bias[n0 + wc * 64 + j * 16 + lm]);
                u16 pk[4];
#pragma unroll
                for (int r = 0; r < 4; r++) pk[r] = f2b(acc[i][j][r] + bv_);
                *(v4s*)&Vth[((size_t)(b * 16 + h) * 64 + d) * 2048 + pos] = *(const v4s*)pk;
            }
        }
    }
}

// ---------------- flash attention v5: transposed-S, zero LDS, L1-cooperative blocks ----------------
// Block = 4 waves on 4 ADJACENT 16-row q-tiles of the same head (64 rows).
// All waves have identical chunk count (g+1) -> natural lockstep; each 16 KB
// K/V chunk is fetched once into the CU's L1 and reused by all 4 waves.
// Grid quarters map g as {g8, 15-g8, 16+g8, 31-g8} so per-CU work is constant.
__global__ __launch_bounds__(256, 4) void attn5_k(const u16* __restrict__ Qh,
                                                  const u16* __restrict__ Kh,
                                                  const u16* __restrict__ Vth,
                                                  u16* __restrict__ out) {
    const int tid = threadIdx.x;
    const int wid = tid >> 6, lane = tid & 63;
    const int lg = lane >> 4, lm = lane & 15;
    const int i = blockIdx.x;
    const int q = i >> 8, s = i & 255;
    const int bh = s & 31;
    const int g8 = s >> 5;                        // 0..7
    const int g = (q == 0) ? g8 : (q == 1) ? (15 - g8) : (q == 2) ? (16 + g8) : (31 - g8);
    const int q0 = g * 64 + wid * 16;             // this wave's 16-row tile
    const int qrow_l = q0 + lm;                   // this lane's softmax row
    const size_t qkb = (size_t)bh * 2048;
    const u16* Vb = Vth + (size_t)bh * 64 * 2048;
    const v4f vzero = {0.f, 0.f, 0.f, 0.f};
    const float sc = 0.18033688011f; // log2(e)/8

    v8s aq[2];
    {
        const u16* qp = Qh + (qkb + q0 + lm) * 64 + lg * 8;
        aq[0] = *(const v8s*)qp;
        aq[1] = *(const v8s*)(qp + 32);
    }
    float m_run = -1e30f, l_run = 0.f;
    v4f o[4];   // O^T tiles: lane holds qrow=lm, d = dt*16 + lg*4 + r
#pragma unroll
    for (int dt = 0; dt < 4; dt++) o[dt] = vzero;

    const int nchunks = g + 1;            // keys 0..q0+15 in 64-key chunks (same for all 4 waves)
    for (int ci = 0; ci < nchunks; ++ci) {
        const int k0 = ci << 6;
        // ---- S^T = K·Q^T over 64 keys: 4 key-subtiles of 16 ----
        v4f sacc[4];
#pragma unroll
        for (int kt = 0; kt < 4; kt++) {
            const u16* kp = Kh + (qkb + k0 + kt * 16 + lm) * 64 + lg * 8;
            v8s k0f = *(const v8s*)kp;
            v8s k1f = *(const v8s*)(kp + 32);
            sacc[kt] = __builtin_amdgcn_mfma_f32_16x16x32_bf16(k0f, aq[0], vzero, 0, 0, 0);
            sacc[kt] = __builtin_amdgcn_mfma_f32_16x16x32_bf16(k1f, aq[1], sacc[kt], 0, 0, 0);
        }
        float vv[4][4];
#pragma unroll
        for (int kt = 0; kt < 4; kt++)
#pragma unroll
            for (int r = 0; r < 4; r++) vv[kt][r] = sacc[kt][r] * sc;
        if (k0 + 63 > q0) {   // diagonal chunk only (wave-uniform branch)
#pragma unroll
            for (int kt = 0; kt < 4; kt++)
#pragma unroll
                for (int r = 0; r < 4; r++)
                    if (k0 + kt * 16 + lg * 4 + r > qrow_l) vv[kt][r] = -1e30f;
        }
        float mt = -1e30f;
#pragma unroll
        for (int kt = 0; kt < 4; kt++)
#pragma unroll
            for (int r = 0; r < 4; r++) mt = fmaxf(mt, vv[kt][r]);
        mt = fmaxf(mt, __shfl_xor(mt, 16, 64));
        mt = fmaxf(mt, __shfl_xor(mt, 32, 64));
        const float mn = fmaxf(m_run, mt);
        const float al = exp2f(m_run - mn);
        m_run = mn;
        float rs = 0.f;
        v8s B0, B1;
#pragma unroll
        for (int kt = 0; kt < 4; kt++)
#pragma unroll
            for (int r = 0; r < 4; r++) {
                float p = exp2f(vv[kt][r] - mn);
                rs += p;
                const u16 pb = f2b(p);
                if (kt < 2) B0[kt * 4 + r] = (short)pb;
                else        B1[(kt - 2) * 4 + r] = (short)pb;
            }
        rs += __shfl_xor(rs, 16, 64);
        rs += __shfl_xor(rs, 32, 64);
        l_run = l_run * al + rs;
#pragma unroll
        for (int dt = 0; dt < 4; dt++) o[dt] *= al;
        // ---- O^T += V^T P^T over the same 64 keys (2 permuted 32-key blocks) ----
#pragma unroll
        for (int dt = 0; dt < 4; dt++) {
            const u16* vp = Vb + (size_t)(dt * 16 + lm) * 2048 + k0 + lg * 8;
            v8s va0 = *(const v8s*)vp;
            v8s va1 = *(const v8s*)(vp + 32);
            o[dt] = __builtin_amdgcn_mfma_f32_16x16x32_bf16(va0, B0, o[dt], 0, 0, 0);
            o[dt] = __builtin_amdgcn_mfma_f32_16x16x32_bf16(va1, B1, o[dt], 0, 0, 0);
        }
    }
    const int b = bh >> 4, h = bh & 15;
    const float inv = 1.0f / l_run;
    const size_t rowb = ((size_t)b * 2048 + q0 + lm) * 1024 + h * 64;
#pragma unroll
    for (int dt = 0; dt < 4; dt++) {
        u16 pk[4];
#pragma unroll
        for (int r = 0; r < 4; r++) pk[r] = f2b(o[dt][r] * inv);
        *(v4s*)&out[rowb + dt * 16 + lg * 4] = *(const v4s*)pk;
    }
}

extern "C" void kernel_launch(void* const* d_in, const int* in_sizes, int n_in,
                              void* d_out, int out_size, void* d_ws, size_t ws_size,
                              hipStream_t stream) {
    const void* x      = d_in[0];
    const void* ln1_g  = d_in[1];
    const void* ln1_b  = d_in[2];
    const void* w_attn = d_in[3];
    const void* b_attn = d_in[4];
    const void* w_proj = d_in[5];
    const void* b_proj = d_in[6];
    const void* ln2_g  = d_in[7];
    const void* ln2_b  = d_in[8];
    const void* w_fc   = d_in[9];
    const void* b_fc   = d_in[10];
    const void* w_fc2  = d_in[11];
    const void* b_fc2  = d_in[12];

    u16* ws = (u16*)d_ws;
    const size_t Mi = 1u << 20;
    u16* xb       = ws;                 // [0,4Mi)
    u16* ln_buf   = ws + 4 * Mi;        // [4,8)
    u16* h_buf    = ws + 8 * Mi;        // [8,12)
    u16* wT_attn  = ws + 12 * Mi;       // [12,15)
    u16* wT_proj  = ws + 15 * Mi;       // [15,16)
    u16* wT_fc    = ws + 16 * Mi;       // [16,20)
    u16* wT_fc2   = ws + 20 * Mi;       // [20,24)
    u16* bb       = ws + 24 * Mi;
    u16* bb_attn = bb, *bb_proj = bb + 4096, *bb_fc = bb + 8192, *bb_fc2 = bb + 12288;
    u16* gsmall   = bb + 16384;
    u16* g_ln1g = gsmall, *g_ln1b = gsmall + 1024, *g_ln2g = gsmall + 2048, *g_ln2b = gsmall + 3072;
    int* flag     = (int*)(bb + 24576);
    u16* Qh       = ws + 25 * Mi;       // [25,29) head-major Q
    u16* Kh       = ws + 29 * Mi;       // [29,33)
    u16* Vth      = ws + 33 * Mi;       // [33,37) V^T permuted [bh][d][pos(t)]
    u16* attn_buf = ws + 37 * Mi;       // [37,41)
    u16* fc_buf   = ws + 25 * Mi;       // [25,41) overlays dead Qh/Kh/Vth/attn_buf
    // total 41 Mi u16 = 82 MiB

    detect_k<<<1, 256, 0, stream>>>(x, flag);

    cvt_k<<<4096, 256, 0, stream>>>(x, xb, 4 * Mi, flag);
    P8 smalls;
    smalls.p[0] = b_attn; smalls.p[1] = b_proj; smalls.p[2] = b_fc; smalls.p[3] = b_fc2;
    smalls.p[4] = ln1_g;  smalls.p[5] = ln1_b;  smalls.p[6] = ln2_g; smalls.p[7] = ln2_b;
    cvt_small_k<<<52, 256, 0, stream>>>(smalls, bb, flag);

    dim3 tb(32, 8);
    transpose_k<<<dim3(96, 32), tb, 0, stream>>>(w_attn, wT_attn, 1024, 3072, flag);
    transpose_k<<<dim3(32, 32), tb, 0, stream>>>(w_proj, wT_proj, 1024, 1024, flag);
    transpose_k<<<dim3(128, 32), tb, 0, stream>>>(w_fc, wT_fc, 1024, 4096, flag);
    transpose_k<<<dim3(32, 128), tb, 0, stream>>>(w_fc2, wT_fc2, 4096, 1024, flag);

    layernorm_k<<<1024, 256, 0, stream>>>(xb, g_ln1g, g_ln1b, ln_buf);
    gemm_qkv_k<<<dim3(24, 32), 256, 0, stream>>>(ln_buf, wT_attn, bb_attn, Qh, Kh, Vth);
    attn5_k<<<1024, 256, 0, stream>>>(Qh, Kh, Vth, attn_buf);
    gemm_bt_k<<<dim3(8, 32), 256, 0, stream>>>(attn_buf, wT_proj, bb_proj, xb, h_buf,
                                               4096, 1024, 1024, 0, nullptr);
    layernorm_k<<<1024, 256, 0, stream>>>(h_buf, g_ln2g, g_ln2b, ln_buf);
    gemm_bt_k<<<dim3(32, 32), 256, 0, stream>>>(ln_buf, wT_fc, bb_fc, nullptr, fc_buf,
                                                4096, 4096, 1024, 1, nullptr);
    gemm_bt_k<<<dim3(8, 32), 256, 0, stream>>>(fc_buf, wT_fc2, bb_fc2, h_buf, d_out,
                                               4096, 1024, 4096, 0, flag);
}

// Round 8
// 544.098 us; speedup vs baseline: 1.1763x; 1.0017x over previous
//
#include <hip/hip_runtime.h>

typedef unsigned short u16;
typedef unsigned int u32;
typedef short v8s __attribute__((ext_vector_type(8)));
typedef short v4s __attribute__((ext_vector_type(4)));
typedef float v4f __attribute__((ext_vector_type(4)));

__device__ __forceinline__ float b2f(u16 v) {
    return __uint_as_float(((u32)v) << 16);
}
__device__ __forceinline__ u16 f2b(float f) {
    u32 u = __float_as_uint(f);
    return (u16)((u + 0x7FFFu + ((u >> 16) & 1u)) >> 16);
}

// ---------------- dtype detect: bf16 vs f32 reinterpretation ----------------
__global__ void detect_k(const void* x, int* flag) {
    __shared__ int cnt;
    if (threadIdx.x == 0) cnt = 0;
    __syncthreads();
    const u16* p = (const u16*)x;
    int bad = 0;
    for (int i = threadIdx.x; i < 4096; i += 256) {
        int e = (p[i] >> 7) & 0xFF;
        if (e != 0 && (e < 100 || e > 140)) bad++;
    }
    atomicAdd(&cnt, bad);
    __syncthreads();
    if (threadIdx.x == 0) *flag = (cnt > 256) ? 1 : 0;
}

// ---------------- convert to bf16 (grid-stride) ----------------
__global__ void cvt_k(const void* __restrict__ src, u16* __restrict__ dst, int n,
                      const int* __restrict__ flag) {
    const int isf32 = *flag;
    for (int i = blockIdx.x * 256 + threadIdx.x; i < n; i += gridDim.x * 256)
        dst[i] = isf32 ? f2b(((const float*)src)[i]) : ((const u16*)src)[i];
}

// ---------------- fused small-tensor convert (biases + ln params) ----------------
struct P8 { const void* p[8]; };
__global__ void cvt_small_k(P8 src, u16* __restrict__ bb, const int* __restrict__ flag) {
    const int isf32 = *flag;
    const int len[8] = {3072, 1024, 4096, 1024, 1024, 1024, 1024, 1024};
    const int doff[8] = {0, 4096, 8192, 12288, 16384, 17408, 18432, 19456};
    int gi = blockIdx.x * 256 + threadIdx.x;
    int seg = 0, off = gi;
    while (seg < 7 && off >= len[seg]) { off -= len[seg]; seg++; }
    if (off < len[seg]) {
        const void* s = src.p[seg];
        bb[doff[seg] + off] = isf32 ? f2b(((const float*)s)[off]) : ((const u16*)s)[off];
    }
}

// ---------------- transpose+convert: in[R][C] -> out[C][R] bf16 ----------------
__global__ void transpose_k(const void* __restrict__ in, u16* __restrict__ out, int R, int C,
                            const int* __restrict__ flag) {
    __shared__ u16 t[32][33];
    const int isf32 = *flag;
    const int c0 = blockIdx.x * 32, r0 = blockIdx.y * 32;
    for (int i = threadIdx.y; i < 32; i += 8) {
        size_t idx = (size_t)(r0 + i) * C + c0 + threadIdx.x;
        t[i][threadIdx.x] = isf32 ? f2b(((const float*)in)[idx]) : ((const u16*)in)[idx];
    }
    __syncthreads();
    for (int i = threadIdx.y; i < 32; i += 8)
        out[(size_t)(c0 + i) * R + r0 + threadIdx.x] = t[threadIdx.x][i];
}

// ---------------- layernorm: one wave per 1024-elem row (bf16 in ws) ----------------
__global__ __launch_bounds__(256) void layernorm_k(const u16* __restrict__ x,
                                                   const u16* __restrict__ g,
                                                   const u16* __restrict__ bta,
                                                   u16* __restrict__ out) {
    const int wid = threadIdx.x >> 6, lane = threadIdx.x & 63;
    const size_t row = (size_t)blockIdx.x * 4 + wid;
    const u16* xr = x + row * 1024 + lane * 16;
    u16 v[16];
    *(uint4*)&v[0] = *(const uint4*)xr;
    *(uint4*)&v[8] = *(const uint4*)(xr + 8);
    float f[16], s = 0.f, sq = 0.f;
#pragma unroll
    for (int i = 0; i < 16; i++) { f[i] = b2f(v[i]); s += f[i]; sq += f[i] * f[i]; }
#pragma unroll
    for (int d = 1; d < 64; d <<= 1) { s += __shfl_xor(s, d, 64); sq += __shfl_xor(sq, d, 64); }
    const float mean = s * (1.f / 1024.f);
    const float var = sq * (1.f / 1024.f) - mean * mean;
    const float rstd = rsqrtf(var + 1e-5f);
    u16 gv[16], bv[16];
    *(uint4*)&gv[0] = *(const uint4*)(g + lane * 16);
    *(uint4*)&gv[8] = *(const uint4*)(g + lane * 16 + 8);
    *(uint4*)&bv[0] = *(const uint4*)(bta + lane * 16);
    *(uint4*)&bv[8] = *(const uint4*)(bta + lane * 16 + 8);
    u16 ov[16];
#pragma unroll
    for (int i = 0; i < 16; i++) ov[i] = f2b((f[i] - mean) * rstd * b2f(gv[i]) + b2f(bv[i]));
    u16* orow = out + row * 1024 + lane * 16;
    *(uint4*)orow = *(uint4*)&ov[0];
    *(uint4*)(orow + 8) = *(uint4*)&ov[8];
}

// ---------------- generic GEMM: C[M][N] = A @ Bt^T + bias (+gelu) (+res) ----------------
__global__ __launch_bounds__(256) void gemm_bt_k(const u16* __restrict__ A,
                                                 const u16* __restrict__ Bt,
                                                 const u16* __restrict__ bias,
                                                 const u16* __restrict__ res,
                                                 void* __restrict__ C,
                                                 int M, int N, int K, int do_gelu,
                                                 const int* __restrict__ outf32) {
    __shared__ __align__(16) u16 As[128 * 32];
    __shared__ __align__(16) u16 Bs[128 * 32];
    const int tid = threadIdx.x;
    const int wid = tid >> 6, lane = tid & 63;
    const int lg = lane >> 4, lm = lane & 15;
    const int wr = wid >> 1, wc = wid & 1;
    const int m0 = blockIdx.y * 128, n0 = blockIdx.x * 128;

    const v4f vzero = {0.f, 0.f, 0.f, 0.f};
    v4f acc[4][4];
#pragma unroll
    for (int i = 0; i < 4; i++)
#pragma unroll
        for (int j = 0; j < 4; j++) acc[i][j] = vzero;

    const int srow = tid >> 2;
    const int scol = (tid & 3) * 8;
    const u16* Ag = A + (size_t)(m0 + srow) * K + scol;
    const u16* Bg = Bt + (size_t)(n0 + srow) * K + scol;
    for (int k0 = 0; k0 < K; k0 += 32) {
        v8s a0 = *(const v8s*)(Ag + k0);
        v8s a1 = *(const v8s*)(Ag + (size_t)64 * K + k0);
        v8s b0 = *(const v8s*)(Bg + k0);
        v8s b1 = *(const v8s*)(Bg + (size_t)64 * K + k0);
        __syncthreads();
        *(v8s*)&As[tid * 8] = a0;
        *(v8s*)&As[2048 + tid * 8] = a1;
        *(v8s*)&Bs[tid * 8] = b0;
        *(v8s*)&Bs[2048 + tid * 8] = b1;
        __syncthreads();
        v8s af[4], bf[4];
#pragma unroll
        for (int i = 0; i < 4; i++) af[i] = *(const v8s*)&As[(wr * 64 + i * 16 + lm) * 32 + lg * 8];
#pragma unroll
        for (int j = 0; j < 4; j++) bf[j] = *(const v8s*)&Bs[(wc * 64 + j * 16 + lm) * 32 + lg * 8];
#pragma unroll
        for (int i = 0; i < 4; i++)
#pragma unroll
            for (int j = 0; j < 4; j++)
                acc[i][j] = __builtin_amdgcn_mfma_f32_16x16x32_bf16(af[i], bf[j], acc[i][j], 0, 0, 0);
    }

    const int of32 = outf32 ? *outf32 : 0;
#pragma unroll
    for (int i = 0; i < 4; i++) {
#pragma unroll
        for (int r = 0; r < 4; r++) {
            const int row = m0 + wr * 64 + i * 16 + lg * 4 + r;
            const size_t rb = (size_t)row * N;
#pragma unroll
            for (int j = 0; j < 4; j++) {
                const int col = n0 + wc * 64 + j * 16 + lm;
                float v = acc[i][j][r] + b2f(bias[col]);
                if (do_gelu) v = 0.5f * v * (1.0f + erff(v * 0.70710678118f));
                if (res) v += b2f(res[rb + col]);
                if (of32) ((float*)C)[rb + col] = v;
                else ((u16*)C)[rb + col] = f2b(v);
            }
        }
    }
}

// ---------------- QKV GEMM: head-major Q (pre-scaled by log2e/8) / K + permuted V^T ----------------
__global__ __launch_bounds__(256) void gemm_qkv_k(const u16* __restrict__ A,
                                                  const u16* __restrict__ Bt,
                                                  const u16* __restrict__ bias,
                                                  u16* __restrict__ Qh,
                                                  u16* __restrict__ Kh,
                                                  u16* __restrict__ Vth) {
    __shared__ __align__(16) u16 As[128 * 32];
    __shared__ __align__(16) u16 Bs[128 * 32];
    const int tid = threadIdx.x;
    const int wid = tid >> 6, lane = tid & 63;
    const int lg = lane >> 4, lm = lane & 15;
    const int wr = wid >> 1, wc = wid & 1;
    const int m0 = blockIdx.y * 128, n0 = blockIdx.x * 128;
    const int K = 1024;

    const v4f vzero = {0.f, 0.f, 0.f, 0.f};
    v4f acc[4][4];
#pragma unroll
    for (int i = 0; i < 4; i++)
#pragma unroll
        for (int j = 0; j < 4; j++) acc[i][j] = vzero;

    const int srow = tid >> 2;
    const int scol = (tid & 3) * 8;
    const u16* Ag = A + (size_t)(m0 + srow) * K + scol;
    const u16* Bg = Bt + (size_t)(n0 + srow) * K + scol;
    for (int k0 = 0; k0 < K; k0 += 32) {
        v8s a0 = *(const v8s*)(Ag + k0);
        v8s a1 = *(const v8s*)(Ag + (size_t)64 * K + k0);
        v8s b0 = *(const v8s*)(Bg + k0);
        v8s b1 = *(const v8s*)(Bg + (size_t)64 * K + k0);
        __syncthreads();
        *(v8s*)&As[tid * 8] = a0;
        *(v8s*)&As[2048 + tid * 8] = a1;
        *(v8s*)&Bs[tid * 8] = b0;
        *(v8s*)&Bs[2048 + tid * 8] = b1;
        __syncthreads();
        v8s af[4], bf[4];
#pragma unroll
        for (int i = 0; i < 4; i++) af[i] = *(const v8s*)&As[(wr * 64 + i * 16 + lm) * 32 + lg * 8];
#pragma unroll
        for (int j = 0; j < 4; j++) bf[j] = *(const v8s*)&Bs[(wc * 64 + j * 16 + lm) * 32 + lg * 8];
#pragma unroll
        for (int i = 0; i < 4; i++)
#pragma unroll
            for (int j = 0; j < 4; j++)
                acc[i][j] = __builtin_amdgcn_mfma_f32_16x16x32_bf16(af[i], bf[j], acc[i][j], 0, 0, 0);
    }

    const int which = n0 >> 10;                 // 0=q 1=k 2=v
    const int h = ((n0 & 1023) >> 6) + wc;      // head
    if (which < 2) {
        u16* dst = which ? Kh : Qh;
        const float qsc = which ? 1.0f : 0.18033688011f;  // fold log2(e)/8 into Q
#pragma unroll
        for (int i = 0; i < 4; i++) {
#pragma unroll
            for (int r = 0; r < 4; r++) {
                const int row = m0 + wr * 64 + i * 16 + lg * 4 + r;
                const int b = row >> 11, t = row & 2047;
                const size_t rb = ((size_t)(b * 16 + h) * 2048 + t) * 64;
#pragma unroll
                for (int j = 0; j < 4; j++) {
                    float v = (acc[i][j][r] + b2f(bias[n0 + wc * 64 + j * 16 + lm])) * qsc;
                    dst[rb + j * 16 + lm] = f2b(v);
                }
            }
        }
    } else {
#pragma unroll
        for (int i = 0; i < 4; i++) {
            const int t0 = m0 + wr * 64 + i * 16 + lg * 4;
            const int b = t0 >> 11, tt = t0 & 2047;
            const int w = tt & 31;
            const int pos = (tt & ~31) + ((w & 15) >> 2) * 8 + ((w >> 4) & 1) * 4;
#pragma unroll
            for (int j = 0; j < 4; j++) {
                const int d = j * 16 + lm;
                const float bv_ = b2f(bias[n0 + wc * 64 + j * 16 + lm]);
                u16 pk[4];
#pragma unroll
                for (int r = 0; r < 4; r++) pk[r] = f2b(acc[i][j][r] + bv_);
                *(v4s*)&Vth[((size_t)(b * 16 + h) * 64 + d) * 2048 + pos] = *(const v4s*)pk;
            }
        }
    }
}

// ---------------- flash attention v6: no online-max, register-prefetch pipeline ----------------
// One wave per (bh, 16-q-row tile), 4 adjacent tiles per block (L1 sharing).
// Scores pre-scaled (Q folded): P = exp2(S) directly; fp32 range is ample
// (|S| ~ 7 sigma << 127). No per-chunk cross-lane reduces; single l-reduce at
// the end. K(ci+1)/V(ci+1) prefetched into rotating registers.
__global__ __launch_bounds__(256, 4) void attn6_k(const u16* __restrict__ Qh,
                                                  const u16* __restrict__ Kh,
                                                  const u16* __restrict__ Vth,
                                                  u16* __restrict__ out) {
    const int tid = threadIdx.x;
    const int wid = tid >> 6, lane = tid & 63;
    const int lg = lane >> 4, lm = lane & 15;
    const int i = blockIdx.x;
    const int q = i >> 8, s = i & 255;
    const int bh = s & 31;
    const int g8 = s >> 5;
    const int g = (q == 0) ? g8 : (q == 1) ? (15 - g8) : (q == 2) ? (16 + g8) : (31 - g8);
    const int q0 = g * 64 + wid * 16;
    const int qrow_l = q0 + lm;
    const size_t qkb = (size_t)bh * 2048;
    const v4f vzero = {0.f, 0.f, 0.f, 0.f};

    v8s aq[2];
    {
        const u16* qp = Qh + (qkb + q0 + lm) * 64 + lg * 8;
        aq[0] = *(const v8s*)qp;
        aq[1] = *(const v8s*)(qp + 32);
    }
    float l_run = 0.f;
    v4f o[4];
#pragma unroll
    for (int dt = 0; dt < 4; dt++) o[dt] = vzero;

    const u16* kbase = Kh + (qkb + lm) * 64 + lg * 8;                 // +ci*4096 +kt*1024
    const u16* vbase = Vth + ((size_t)bh * 64 + lm) * 2048 + lg * 8;  // +ci*64 +dt*32768
    const int nchunks = g + 1;

    v8s kf[8], vf[8];
#pragma unroll
    for (int kt = 0; kt < 4; kt++) {
        kf[kt * 2]     = *(const v8s*)(kbase + kt * 1024);
        kf[kt * 2 + 1] = *(const v8s*)(kbase + kt * 1024 + 32);
    }
#pragma unroll
    for (int dt = 0; dt < 4; dt++) {
        vf[dt * 2]     = *(const v8s*)(vbase + dt * 32768);
        vf[dt * 2 + 1] = *(const v8s*)(vbase + dt * 32768 + 32);
    }

    for (int ci = 0; ci < nchunks; ++ci) {
        const int k0 = ci << 6;
        // ---- S^T = K·Q^T (Q pre-scaled) ----
        v4f sacc[4];
#pragma unroll
        for (int kt = 0; kt < 4; kt++) {
            sacc[kt] = __builtin_amdgcn_mfma_f32_16x16x32_bf16(kf[kt * 2], aq[0], vzero, 0, 0, 0);
            sacc[kt] = __builtin_amdgcn_mfma_f32_16x16x32_bf16(kf[kt * 2 + 1], aq[1], sacc[kt], 0, 0, 0);
        }
        // ---- prefetch next K (clamped; K regs free after MFMA issue) ----
        const int cn = (ci + 1 < nchunks) ? (ci + 1) : ci;
        const u16* kb2 = kbase + cn * 4096;
#pragma unroll
        for (int kt = 0; kt < 4; kt++) {
            kf[kt * 2]     = *(const v8s*)(kb2 + kt * 1024);
            kf[kt * 2 + 1] = *(const v8s*)(kb2 + kt * 1024 + 32);
        }
        // ---- P = exp2(S), causal mask only on diagonal chunk ----
        const bool dm = (ci == nchunks - 1);
        float p[16];
#pragma unroll
        for (int kt = 0; kt < 4; kt++)
#pragma unroll
            for (int r = 0; r < 4; r++) {
                float v = sacc[kt][r];
                v = (dm && (k0 + kt * 16 + lg * 4 + r > qrow_l)) ? -200.f : v;
                p[kt * 4 + r] = exp2f(v);
            }
        float ls = 0.f;
#pragma unroll
        for (int e = 0; e < 16; e++) ls += p[e];
        l_run += ls;
        // ---- pack to bf16 pairs via v_perm ----
        u32 pk[8];
#pragma unroll
        for (int j = 0; j < 8; j++) {
            u32 lo = __float_as_uint(p[j * 2]) + 0x8000u;
            u32 hi = __float_as_uint(p[j * 2 + 1]) + 0x8000u;
            pk[j] = __builtin_amdgcn_perm(hi, lo, 0x07060302u);
        }
        v8s B0, B1;
        ((u32*)&B0)[0] = pk[0]; ((u32*)&B0)[1] = pk[1];
        ((u32*)&B0)[2] = pk[2]; ((u32*)&B0)[3] = pk[3];
        ((u32*)&B1)[0] = pk[4]; ((u32*)&B1)[1] = pk[5];
        ((u32*)&B1)[2] = pk[6]; ((u32*)&B1)[3] = pk[7];
        // ---- O^T += V^T P^T ----
#pragma unroll
        for (int dt = 0; dt < 4; dt++) {
            o[dt] = __builtin_amdgcn_mfma_f32_16x16x32_bf16(vf[dt * 2], B0, o[dt], 0, 0, 0);
            o[dt] = __builtin_amdgcn_mfma_f32_16x16x32_bf16(vf[dt * 2 + 1], B1, o[dt], 0, 0, 0);
        }
        // ---- prefetch next V ----
        const u16* vb2 = vbase + cn * 64;
#pragma unroll
        for (int dt = 0; dt < 4; dt++) {
            vf[dt * 2]     = *(const v8s*)(vb2 + dt * 32768);
            vf[dt * 2 + 1] = *(const v8s*)(vb2 + dt * 32768 + 32);
        }
    }
    l_run += __shfl_xor(l_run, 16, 64);
    l_run += __shfl_xor(l_run, 32, 64);
    const int b = bh >> 4, h = bh & 15;
    const float inv = 1.0f / l_run;
    const size_t rowb = ((size_t)b * 2048 + q0 + lm) * 1024 + h * 64;
#pragma unroll
    for (int dt = 0; dt < 4; dt++) {
        u16 pk2[4];
#pragma unroll
        for (int r = 0; r < 4; r++) pk2[r] = f2b(o[dt][r] * inv);
        *(v4s*)&out[rowb + dt * 16 + lg * 4] = *(const v4s*)pk2;
    }
}

extern "C" void kernel_launch(void* const* d_in, const int* in_sizes, int n_in,
                              void* d_out, int out_size, void* d_ws, size_t ws_size,
                              hipStream_t stream) {
    const void* x      = d_in[0];
    const void* ln1_g  = d_in[1];
    const void* ln1_b  = d_in[2];
    const void* w_attn = d_in[3];
    const void* b_attn = d_in[4];
    const void* w_proj = d_in[5];
    const void* b_proj = d_in[6];
    const void* ln2_g  = d_in[7];
    const void* ln2_b  = d_in[8];
    const void* w_fc   = d_in[9];
    const void* b_fc   = d_in[10];
    const void* w_fc2  = d_in[11];
    const void* b_fc2  = d_in[12];

    u16* ws = (u16*)d_ws;
    const size_t Mi = 1u << 20;
    u16* xb       = ws;                 // [0,4Mi)
    u16* ln_buf   = ws + 4 * Mi;        // [4,8)
    u16* h_buf    = ws + 8 * Mi;        // [8,12)
    u16* wT_attn  = ws + 12 * Mi;       // [12,15)
    u16* wT_proj  = ws + 15 * Mi;       // [15,16)
    u16* wT_fc    = ws + 16 * Mi;       // [16,20)
    u16* wT_fc2   = ws + 20 * Mi;       // [20,24)
    u16* bb       = ws + 24 * Mi;
    u16* bb_attn = bb, *bb_proj = bb + 4096, *bb_fc = bb + 8192, *bb_fc2 = bb + 12288;
    u16* gsmall   = bb + 16384;
    u16* g_ln1g = gsmall, *g_ln1b = gsmall + 1024, *g_ln2g = gsmall + 2048, *g_ln2b = gsmall + 3072;
    int* flag     = (int*)(bb + 24576);
    u16* Qh       = ws + 25 * Mi;       // [25,29) head-major Q (pre-scaled)
    u16* Kh       = ws + 29 * Mi;       // [29,33)
    u16* Vth      = ws + 33 * Mi;       // [33,37) V^T permuted [bh][d][pos(t)]
    u16* attn_buf = ws + 37 * Mi;       // [37,41)
    u16* fc_buf   = ws + 25 * Mi;       // [25,41) overlays dead Qh/Kh/Vth/attn_buf
    // total 41 Mi u16 = 82 MiB

    detect_k<<<1, 256, 0, stream>>>(x, flag);

    cvt_k<<<4096, 256, 0, stream>>>(x, xb, 4 * Mi, flag);
    P8 smalls;
    smalls.p[0] = b_attn; smalls.p[1] = b_proj; smalls.p[2] = b_fc; smalls.p[3] = b_fc2;
    smalls.p[4] = ln1_g;  smalls.p[5] = ln1_b;  smalls.p[6] = ln2_g; smalls.p[7] = ln2_b;
    cvt_small_k<<<52, 256, 0, stream>>>(smalls, bb, flag);

    dim3 tb(32, 8);
    transpose_k<<<dim3(96, 32), tb, 0, stream>>>(w_attn, wT_attn, 1024, 3072, flag);
    transpose_k<<<dim3(32, 32), tb, 0, stream>>>(w_proj, wT_proj, 1024, 1024, flag);
    transpose_k<<<dim3(128, 32), tb, 0, stream>>>(w_fc, wT_fc, 1024, 4096, flag);
    transpose_k<<<dim3(32, 128), tb, 0, stream>>>(w_fc2, wT_fc2, 4096, 1024, flag);

    layernorm_k<<<1024, 256, 0, stream>>>(xb, g_ln1g, g_ln1b, ln_buf);
    gemm_qkv_k<<<dim3(24, 32), 256, 0, stream>>>(ln_buf, wT_attn, bb_attn, Qh, Kh, Vth);
    attn6_k<<<1024, 256, 0, stream>>>(Qh, Kh, Vth, attn_buf);
    gemm_bt_k<<<dim3(8, 32), 256, 0, stream>>>(attn_buf, wT_proj, bb_proj, xb, h_buf,
                                               4096, 1024, 1024, 0, nullptr);
    layernorm_k<<<1024, 256, 0, stream>>>(h_buf, g_ln2g, g_ln2b, ln_buf);
    gemm_bt_k<<<dim3(32, 32), 256, 0, stream>>>(ln_buf, wT_fc, bb_fc, nullptr, fc_buf,
                                                4096, 4096, 1024, 1, nullptr);
    gemm_bt_k<<<dim3(8, 32), 256, 0, stream>>>(fc_buf, wT_fc2, bb_fc2, h_buf, d_out,
                                               4096, 1024, 4096, 0, flag);
}